// Round 2
// baseline (464.817 us; speedup 1.0000x reference)
//
#include <hip/hip_runtime.h>

#define NROWS 16384   // B*L
#define LSEQ  2048
#define NB    8

typedef short v8s __attribute__((ext_vector_type(8)));
typedef float v4f __attribute__((ext_vector_type(4)));

__device__ __forceinline__ unsigned short f2bf(float f) {
    unsigned int u = __float_as_uint(f);
    return (unsigned short)((u + 0x7fffu + ((u >> 16) & 1u)) >> 16);
}
__device__ __forceinline__ float bf2f(unsigned short u) {
    return __uint_as_float(((unsigned int)u) << 16);
}

// ------- tiled transpose + fp32->bf16 convert: out[c*ldo + r] = bf16(in[r*C + c]) -------
__global__ void transpose_kernel(const float* __restrict__ in, int R, int C,
                                 unsigned short* __restrict__ out, int ldo) {
    __shared__ unsigned short tile[32][33];
    int c0 = blockIdx.x * 32, r0 = blockIdx.y * 32;
    int tx = threadIdx.x, ty = threadIdx.y;
    for (int i = ty; i < 32; i += 8) {
        int r = r0 + i, c = c0 + tx;
        tile[i][tx] = (r < R && c < C) ? f2bf(in[r * C + c]) : (unsigned short)0;
    }
    __syncthreads();
    for (int i = ty; i < 32; i += 8) {
        int c = c0 + i, r = r0 + tx;
        if (r < R && c < C) out[c * ldo + r] = tile[tx][i];
    }
}

// ------- elementwise fp32 -> bf16 convert -------
__global__ void convert_kernel(const float* __restrict__ in, unsigned short* __restrict__ out, int n) {
    int i = blockIdx.x * 256 + threadIdx.x;
    if (i < n) out[i] = f2bf(in[i]);
}

// ------- embedding gather + pos add -> fp32 x -------
__global__ void embed_kernel(const int* __restrict__ ids, const float* __restrict__ tok,
                             const float* __restrict__ pos, float* __restrict__ x) {
    int row = blockIdx.x;            // b*LSEQ + l
    int l = row & (LSEQ - 1);
    int d = threadIdx.x * 4;         // 128 threads
    int id = ids[row];
    float4 tv = *(const float4*)(tok + id * 512 + d);
    float4 pv = *(const float4*)(pos + l * 512 + d);
    float4 o = make_float4(tv.x + pv.x, tv.y + pv.y, tv.z + pv.z, tv.w + pv.w);
    *(float4*)(x + row * 512 + d) = o;
}

// ------- LayerNorm over D=512, fp32 in -> bf16 out -------
__global__ __launch_bounds__(256) void ln_kernel(const float* __restrict__ x,
        const float* __restrict__ g, const float* __restrict__ b,
        unsigned short* __restrict__ out) {
    int row = blockIdx.x;
    int t = threadIdx.x;
    const float* xr = x + row * 512;
    float a0 = xr[t], a1 = xr[t + 256];
    float s = a0 + a1, s2 = a0 * a0 + a1 * a1;
    #pragma unroll
    for (int o = 32; o > 0; o >>= 1) { s += __shfl_down(s, o); s2 += __shfl_down(s2, o); }
    __shared__ float ps[4], ps2[4], mv[2];
    int w = t >> 6;
    if ((t & 63) == 0) { ps[w] = s; ps2[w] = s2; }
    __syncthreads();
    if (t == 0) {
        float S = ps[0] + ps[1] + ps[2] + ps[3];
        float S2 = ps2[0] + ps2[1] + ps2[2] + ps2[3];
        float m = S * (1.0f / 512.0f);
        float var = S2 * (1.0f / 512.0f) - m * m;
        mv[0] = m; mv[1] = 1.0f / sqrtf(var + 1e-5f);
    }
    __syncthreads();
    float m = mv[0], r = mv[1];
    out[row * 512 + t]       = f2bf((a0 - m) * r * g[t]       + b[t]);
    out[row * 512 + t + 256] = f2bf((a1 - m) * r * g[t + 256] + b[t + 256]);
}

// ------- MFMA GEMM: C[M,N] = A[M,K] * BT[N,K]^T, fused epilogues -------
#define EPI_GELU_BF16 0
#define EPI_RES_F32   1
#define EPI_TANH_BF16 2
#define EPI_F32       3

template <int EPI>
__global__ __launch_bounds__(256) void gemm_kernel(
        const unsigned short* __restrict__ A, int lda,
        const unsigned short* __restrict__ BT, int ldb,
        const float* __restrict__ bias,
        const float* __restrict__ resid,
        void* __restrict__ Cout, int ldc, int N, int K) {
    __shared__ unsigned short As[128][40] __attribute__((aligned(16)));
    __shared__ unsigned short Bs[128][40] __attribute__((aligned(16)));
    int t = threadIdx.x;
    int lane = t & 63, wave = t >> 6;
    int quad = lane >> 4, l16 = lane & 15;
    int wm = (wave >> 1) * 64, wn = (wave & 1) * 64;
    int tileM = blockIdx.x * 128, tileN = blockIdx.y * 128;
    int arow = t >> 2, acol = (t & 3) * 8;

    v4f acc[4][4] = {};

    for (int k0 = 0; k0 < K; k0 += 32) {
        const unsigned short* ap = A + (tileM + arow) * lda + k0 + acol;
        uint4 a0 = *(const uint4*)ap;
        uint4 a1 = *(const uint4*)(ap + 64 * lda);
        uint4 b0 = make_uint4(0u, 0u, 0u, 0u), b1 = make_uint4(0u, 0u, 0u, 0u);
        int bn0 = tileN + arow;
        if (bn0 < N)      b0 = *(const uint4*)(BT + bn0 * ldb + k0 + acol);
        if (bn0 + 64 < N) b1 = *(const uint4*)(BT + (bn0 + 64) * ldb + k0 + acol);
        __syncthreads();
        *(uint4*)&As[arow][acol]      = a0;
        *(uint4*)&As[arow + 64][acol] = a1;
        *(uint4*)&Bs[arow][acol]      = b0;
        *(uint4*)&Bs[arow + 64][acol] = b1;
        __syncthreads();
        v8s af[4], bf[4];
        #pragma unroll
        for (int i = 0; i < 4; ++i) af[i] = *(const v8s*)&As[wm + i * 16 + l16][quad * 8];
        #pragma unroll
        for (int j = 0; j < 4; ++j) bf[j] = *(const v8s*)&Bs[wn + j * 16 + l16][quad * 8];
        #pragma unroll
        for (int i = 0; i < 4; ++i)
            #pragma unroll
            for (int j = 0; j < 4; ++j)
                acc[i][j] = __builtin_amdgcn_mfma_f32_16x16x32_bf16(af[i], bf[j], acc[i][j], 0, 0, 0);
    }

    // D layout: col = lane&15, row = quad*4 + reg  (m89/m91-verified)
    #pragma unroll
    for (int i = 0; i < 4; ++i) {
        #pragma unroll
        for (int j = 0; j < 4; ++j) {
            int col = tileN + wn + j * 16 + l16;
            if (col >= N) continue;
            #pragma unroll
            for (int r = 0; r < 4; ++r) {
                int row = tileM + wm + i * 16 + quad * 4 + r;
                float v = acc[i][j][r];
                if (EPI == EPI_GELU_BF16) {
                    v += bias[col];
                    v = 0.5f * v * (1.0f + erff(v * 0.70710678118654752f));
                    ((unsigned short*)Cout)[row * ldc + col] = f2bf(v);
                } else if (EPI == EPI_RES_F32) {
                    v += bias[col] + resid[row * ldc + col];
                    ((float*)Cout)[row * ldc + col] = v;
                } else if (EPI == EPI_TANH_BF16) {
                    ((unsigned short*)Cout)[row * ldc + col] = f2bf(tanhf(v));
                } else {
                    ((float*)Cout)[row * ldc + col] = v;
                }
            }
        }
    }
}

// ------- exact ordered-triplet scan: 16 segments x 128 rows, combine in-block -------
__global__ __launch_bounds__(1024) void scan_kernel(const float* __restrict__ u, float* __restrict__ s) {
    int b = blockIdx.x;
    int t = threadIdx.x;
    int w = t >> 6, c = t & 63;          // 16 waves, 64 classes
    int l0 = w * 128;
    int l1 = l0 + 128; if (l1 > 2047) l1 = 2047;
    float sA = 0.f, sB = 0.f, sC = 0.f, T = 0.f, M = 0.f, U = 0.f;
    const float* base = u + (b * LSEQ + l0) * 192 + c;
    for (int l = l0; l < l1; ++l) {
        float ua = base[0], ub = base[64], uc = base[128];
        base += 192;
        U += uc * T;
        M += uc * sB;
        T += ub * sA;
        sA += ua; sB += ub; sC += uc;
    }
    __shared__ float sm[16][6][64];
    sm[w][0][c] = sA; sm[w][1][c] = sB; sm[w][2][c] = sC;
    sm[w][3][c] = T;  sm[w][4][c] = M;  sm[w][5][c] = U;
    __syncthreads();
    if (t < 64) {
        float A = sm[0][0][c], B = sm[0][1][c], Tt = sm[0][3][c], Mt = sm[0][4][c], Ut = sm[0][5][c];
        #pragma unroll
        for (int ww = 1; ww < 16; ++ww) {
            float a2 = sm[ww][0][c], b2 = sm[ww][1][c], c2 = sm[ww][2][c];
            float t2 = sm[ww][3][c], m2 = sm[ww][4][c], u2 = sm[ww][5][c];
            float Un = Ut + u2 + c2 * Tt + A * m2;
            float Tn = Tt + t2 + A * b2;
            float Mn = Mt + m2 + B * c2;
            A += a2; B += b2;
            Ut = Un; Tt = Tn; Mt = Mn;
        }
        s[b * 64 + c] = Ut;
    }
}

// ------- final: LN(x[:, -1]) @ Wq + bq + s/denom -> fp32 out -------
__global__ __launch_bounds__(64) void final_kernel(const float* __restrict__ x,
        const float* __restrict__ s,
        const float* __restrict__ qw, const float* __restrict__ qb,
        const float* __restrict__ Wq, const float* __restrict__ bq,
        float* __restrict__ out, float inv_denom) {
    int b = blockIdx.x;
    int c = threadIdx.x;   // 64
    __shared__ float q[512];
    __shared__ float mv[2];
    const float* xr = x + (b * LSEQ + (LSEQ - 1)) * 512;
    float s1 = 0.f, s2 = 0.f;
    for (int i = c; i < 512; i += 64) { float v = xr[i]; q[i] = v; s1 += v; s2 += v * v; }
    #pragma unroll
    for (int o = 32; o > 0; o >>= 1) { s1 += __shfl_down(s1, o); s2 += __shfl_down(s2, o); }
    if (c == 0) {
        float m = s1 * (1.0f / 512.0f);
        float var = s2 * (1.0f / 512.0f) - m * m;
        mv[0] = m; mv[1] = 1.0f / sqrtf(var + 1e-5f);
    }
    __syncthreads();
    float m = mv[0], r = mv[1];
    for (int i = c; i < 512; i += 64) q[i] = (q[i] - m) * r * qw[i] + qb[i];
    __syncthreads();
    float acc = 0.f;
    for (int d = 0; d < 512; ++d) acc += q[d] * Wq[d * 64 + c];
    out[b * 64 + c] = s[b * 64 + c] * inv_denom + acc + bq[c];
}

extern "C" void kernel_launch(void* const* d_in, const int* in_sizes, int n_in,
                              void* d_out, int out_size, void* d_ws, size_t ws_size,
                              hipStream_t stream) {
    const int*   token_ids   = (const int*)d_in[0];
    const float* tok_emb     = (const float*)d_in[1];
    const float* pos_emb     = (const float*)d_in[2];
    const float* stem_ln_w   = (const float*)d_in[3];
    const float* stem_ln_b   = (const float*)d_in[4];
    const float* stem_w1     = (const float*)d_in[5];
    const float* stem_b1     = (const float*)d_in[6];
    const float* stem_w2     = (const float*)d_in[7];
    const float* stem_b2     = (const float*)d_in[8];
    const float* role_ln_w   = (const float*)d_in[9];
    const float* role_ln_b   = (const float*)d_in[10];
    const float* Wa          = (const float*)d_in[11];
    const float* Wb          = (const float*)d_in[12];
    const float* Wc          = (const float*)d_in[13];
    const float* class_a     = (const float*)d_in[14];
    const float* class_b     = (const float*)d_in[15];
    const float* class_c     = (const float*)d_in[16];
    const float* query_ln_w  = (const float*)d_in[17];
    const float* query_ln_b  = (const float*)d_in[18];
    const float* Wq          = (const float*)d_in[19];
    const float* bq          = (const float*)d_in[20];
    float* out = (float*)d_out;

    // workspace layout (~88.3 MB)
    char* wsb = (char*)d_ws;
    float* x             = (float*)(wsb);                       // 33,554,432
    unsigned short* hl   = (unsigned short*)(wsb + 33554432);   // 16,777,216
    unsigned short* Hb   = (unsigned short*)(wsb + 50331648);   // 33,554,432 (ends 83,886,080)
    unsigned short* w1T  = (unsigned short*)(wsb + 83886080);   // 2,097,152
    unsigned short* w2T  = (unsigned short*)(wsb + 85983232);   // 2,097,152
    unsigned short* wabcT= (unsigned short*)(wsb + 88080384);   // 196,608
    unsigned short* clsb = (unsigned short*)(wsb + 88276992);   // 24,576
    float* svec          = (float*)(wsb + 88301568);            // 2,048
    unsigned short* abc  = Hb;                                  // alias (H dead), 6.3 MB
    float* uu            = (float*)(wsb + 58720256);            // alias in Hb, 12.6 MB (disjoint from abc)

    dim3 tb(32, 8);
    transpose_kernel<<<dim3(32, 16), tb, 0, stream>>>(stem_w1,          512, 1024, w1T,          512);
    transpose_kernel<<<dim3(32, 16), tb, 0, stream>>>(stem_w1 + 524288, 512, 1024, w1T + 524288, 512);
    transpose_kernel<<<dim3(16, 32), tb, 0, stream>>>(stem_w2,          1024, 512, w2T,          1024);
    transpose_kernel<<<dim3(16, 32), tb, 0, stream>>>(stem_w2 + 524288, 1024, 512, w2T + 524288, 1024);
    transpose_kernel<<<dim3(2, 16),  tb, 0, stream>>>(Wa, 512, 64, wabcT,         512);
    transpose_kernel<<<dim3(2, 16),  tb, 0, stream>>>(Wb, 512, 64, wabcT + 32768, 512);
    transpose_kernel<<<dim3(2, 16),  tb, 0, stream>>>(Wc, 512, 64, wabcT + 65536, 512);
    convert_kernel<<<16, 256, 0, stream>>>(class_a, clsb,        4096);
    convert_kernel<<<16, 256, 0, stream>>>(class_b, clsb + 4096, 4096);
    convert_kernel<<<16, 256, 0, stream>>>(class_c, clsb + 8192, 4096);

    embed_kernel<<<NROWS, 128, 0, stream>>>(token_ids, tok_emb, pos_emb, x);

    for (int i = 0; i < 2; ++i) {
        ln_kernel<<<NROWS, 256, 0, stream>>>(x, stem_ln_w + i * 512, stem_ln_b + i * 512, hl);
        gemm_kernel<EPI_GELU_BF16><<<dim3(128, 8), 256, 0, stream>>>(
            hl, 512, w1T + i * 524288, 512, stem_b1 + i * 1024, nullptr, Hb, 1024, 1024, 512);
        gemm_kernel<EPI_RES_F32><<<dim3(128, 4), 256, 0, stream>>>(
            Hb, 1024, w2T + i * 524288, 1024, stem_b2 + i * 512, x, x, 512, 512, 1024);
    }

    ln_kernel<<<NROWS, 256, 0, stream>>>(x, role_ln_w, role_ln_b, hl);
    gemm_kernel<EPI_TANH_BF16><<<dim3(128, 2), 256, 0, stream>>>(
        hl, 512, wabcT, 512, nullptr, nullptr, abc, 192, 192, 512);

    for (int j = 0; j < 3; ++j) {
        gemm_kernel<EPI_F32><<<dim3(128, 1), 256, 0, stream>>>(
            abc + j * 64, 192, clsb + j * 4096, 64, nullptr, nullptr, uu + j * 64, 192, 64, 64);
    }

    scan_kernel<<<NB, 1024, 0, stream>>>(uu, svec);

    float inv_denom = (float)(6.0 / (2047.0 * 2046.0 * 2045.0));
    final_kernel<<<NB, 64, 0, stream>>>(x, svec, query_ln_w, query_ln_b, Wq, bq, out, inv_denom);
}

// Round 3
// 448.010 us; speedup vs baseline: 1.0375x; 1.0375x over previous
//
#include <hip/hip_runtime.h>

#define NROWS 16384   // B*L
#define LSEQ  2048
#define NB    8

typedef short v8s __attribute__((ext_vector_type(8)));
typedef float v4f __attribute__((ext_vector_type(4)));

__device__ __forceinline__ unsigned short f2bf(float f) {
    unsigned int u = __float_as_uint(f);
    return (unsigned short)((u + 0x7fffu + ((u >> 16) & 1u)) >> 16);
}

__device__ __forceinline__ void gload16(const unsigned short* g, unsigned short* l) {
    __builtin_amdgcn_global_load_lds(
        (const __attribute__((address_space(1))) unsigned int*)g,
        (__attribute__((address_space(3))) unsigned int*)l, 16, 0, 0);
}

// ------- tiled transpose + fp32->bf16: out[c*ldo + r] = bf16(in[r*C + c]) -------
__global__ void transpose_kernel(const float* __restrict__ in, int R, int C,
                                 unsigned short* __restrict__ out, int ldo) {
    __shared__ unsigned short tile[32][33];
    int c0 = blockIdx.x * 32, r0 = blockIdx.y * 32;
    int tx = threadIdx.x, ty = threadIdx.y;
    for (int i = ty; i < 32; i += 8) {
        int r = r0 + i, c = c0 + tx;
        tile[i][tx] = (r < R && c < C) ? f2bf(in[r * C + c]) : (unsigned short)0;
    }
    __syncthreads();
    for (int i = ty; i < 32; i += 8) {
        int c = c0 + i, r = r0 + tx;
        if (r < R && c < C) out[c * ldo + r] = tile[tx][i];
    }
}

__global__ void convert_kernel(const float* __restrict__ in, unsigned short* __restrict__ out, int n) {
    int i = blockIdx.x * 256 + threadIdx.x;
    if (i < n) out[i] = f2bf(in[i]);
}

// ------- embedding gather + pos add -> fp32 x -------
__global__ void embed_kernel(const int* __restrict__ ids, const float* __restrict__ tok,
                             const float* __restrict__ pos, float* __restrict__ x) {
    int row = blockIdx.x;
    int l = row & (LSEQ - 1);
    int d = threadIdx.x * 4;
    int id = ids[row];
    float4 tv = *(const float4*)(tok + (size_t)id * 512 + d);
    float4 pv = *(const float4*)(pos + l * 512 + d);
    *(float4*)(x + (size_t)row * 512 + d) =
        make_float4(tv.x + pv.x, tv.y + pv.y, tv.z + pv.z, tv.w + pv.w);
}

// ------- LayerNorm over D=512, fp32 in -> bf16 out -------
__global__ __launch_bounds__(256) void ln_kernel(const float* __restrict__ x,
        const float* __restrict__ g, const float* __restrict__ b,
        unsigned short* __restrict__ out) {
    int row = blockIdx.x;
    int t = threadIdx.x;
    const float* xr = x + (size_t)row * 512;
    float a0 = xr[t], a1 = xr[t + 256];
    float s = a0 + a1, s2 = a0 * a0 + a1 * a1;
    #pragma unroll
    for (int o = 32; o > 0; o >>= 1) { s += __shfl_down(s, o); s2 += __shfl_down(s2, o); }
    __shared__ float ps[4], ps2[4], mv[2];
    int w = t >> 6;
    if ((t & 63) == 0) { ps[w] = s; ps2[w] = s2; }
    __syncthreads();
    if (t == 0) {
        float S = ps[0] + ps[1] + ps[2] + ps[3];
        float S2 = ps2[0] + ps2[1] + ps2[2] + ps2[3];
        float m = S * (1.0f / 512.0f);
        float var = S2 * (1.0f / 512.0f) - m * m;
        mv[0] = m; mv[1] = 1.0f / sqrtf(var + 1e-5f);
    }
    __syncthreads();
    float m = mv[0], r = mv[1];
    out[(size_t)row * 512 + t]       = f2bf((a0 - m) * r * g[t]       + b[t]);
    out[(size_t)row * 512 + t + 256] = f2bf((a1 - m) * r * g[t + 256] + b[t + 256]);
}

// ------- MFMA GEMM, m97-style global_load_lds staging + XOR swizzle -------
// LDS layout: position (r, s) holds global chunk s ^ ((r>>1)&3)  (chunks = 8 bf16 = 16B)
#define EPI_GELU_BF16  0
#define EPI_RES_F32    1
#define EPI_TANH_SPLIT 2
#define EPI_F32        3

template <int EPI>
__global__ __launch_bounds__(256) void gemm_kernel(
        const unsigned short* __restrict__ A, int lda,
        const unsigned short* __restrict__ BT, int ldb,
        const float* __restrict__ bias,
        const float* __restrict__ resid,
        void* __restrict__ Cout, int ldc, int N, int K,
        size_t strideAz, size_t strideBz, size_t strideCz) {
    __shared__ unsigned short As[4096] __attribute__((aligned(16)));
    __shared__ unsigned short Bs[4096] __attribute__((aligned(16)));
    int t = threadIdx.x;
    int lane = t & 63, wave = t >> 6;
    int quad = lane >> 4, l16 = lane & 15;
    int wm = (wave >> 1) * 64, wn = (wave & 1) * 64;
    int tileM = blockIdx.x * 128, tileN = blockIdx.y * 128;

    A  += (size_t)blockIdx.z * strideAz;
    BT += (size_t)blockIdx.z * strideBz;

    // staging: lane -> row lr within 16-row group, LDS chunk sc, global chunk qg
    int lr = lane >> 2, sc = lane & 3;
    int qg = sc ^ ((lr >> 1) & 3);
    int ia0 = wave * 2, ia1 = wave * 2 + 1;
    const unsigned short* gA0 = A + (size_t)(tileM + ia0 * 16 + lr) * lda + qg * 8;
    const unsigned short* gA1 = A + (size_t)(tileM + ia1 * 16 + lr) * lda + qg * 8;
    int bn0 = tileN + ia0 * 16 + lr, bn1 = tileN + ia1 * 16 + lr;
    const unsigned short* gB0 = BT + (size_t)bn0 * ldb + qg * 8;
    const unsigned short* gB1 = BT + (size_t)bn1 * ldb + qg * 8;
    bool pb0 = bn0 < N, pb1 = bn1 < N;
    unsigned short* lA0 = As + ia0 * 512;
    unsigned short* lA1 = As + ia1 * 512;
    unsigned short* lB0 = Bs + ia0 * 512;
    unsigned short* lB1 = Bs + ia1 * 512;

    // fragment reads: swizzled chunk = quad ^ ((l16>>1)&3), same for every row group
    int swz = quad ^ ((l16 >> 1) & 3);
    const unsigned short* fA[4];
    const unsigned short* fB[4];
    #pragma unroll
    for (int i = 0; i < 4; ++i) {
        fA[i] = As + (wm + i * 16 + l16) * 32 + swz * 8;
        fB[i] = Bs + (wn + i * 16 + l16) * 32 + swz * 8;
    }

    v4f acc[4][4] = {};

    for (int k0 = 0; k0 < K; k0 += 32) {
        __syncthreads();
        gload16(gA0, lA0);
        gload16(gA1, lA1);
        if (pb0) gload16(gB0, lB0);
        if (pb1) gload16(gB1, lB1);
        gA0 += 32; gA1 += 32; gB0 += 32; gB1 += 32;
        __syncthreads();
        v8s af[4], bfr[4];
        #pragma unroll
        for (int i = 0; i < 4; ++i) af[i] = *(const v8s*)fA[i];
        #pragma unroll
        for (int j = 0; j < 4; ++j) bfr[j] = *(const v8s*)fB[j];
        #pragma unroll
        for (int i = 0; i < 4; ++i)
            #pragma unroll
            for (int j = 0; j < 4; ++j)
                acc[i][j] = __builtin_amdgcn_mfma_f32_16x16x32_bf16(af[i], bfr[j], acc[i][j], 0, 0, 0);
    }

    // D layout: col = lane&15, row = quad*4 + reg
    #pragma unroll
    for (int i = 0; i < 4; ++i) {
        #pragma unroll
        for (int j = 0; j < 4; ++j) {
            int col = tileN + wn + j * 16 + l16;
            if (col >= N) continue;
            #pragma unroll
            for (int r = 0; r < 4; ++r) {
                int row = tileM + wm + i * 16 + quad * 4 + r;
                float v = acc[i][j][r];
                if (EPI == EPI_GELU_BF16) {
                    v += bias[col];
                    v = 0.5f * v * (1.0f + erff(v * 0.70710678118654752f));
                    ((unsigned short*)Cout)[(size_t)row * ldc + col] = f2bf(v);
                } else if (EPI == EPI_RES_F32) {
                    v += bias[col] + resid[(size_t)row * ldc + col];
                    ((float*)Cout)[(size_t)row * ldc + col] = v;
                } else if (EPI == EPI_TANH_SPLIT) {
                    // compact [3][16384][64]
                    ((unsigned short*)Cout)[(size_t)(col >> 6) * 1048576 + (size_t)row * 64 + (col & 63)] = f2bf(tanhf(v));
                } else {
                    ((float*)(((char*)Cout) + 0))[blockIdx.z * strideCz + (size_t)row * ldc + col] = v;
                }
            }
        }
    }
}

// ------- exact ordered-triplet scan, two-pass -------
// per (b,c) over l: U += uc*T; M += uc*sB; T += ub*sA; sA+=ua; sB+=ub; sC+=uc
__global__ __launch_bounds__(64) void scan_part_kernel(const float* __restrict__ u, float* __restrict__ part) {
    int b = blockIdx.x, seg = blockIdx.y;
    int c = threadIdx.x;
    int l0 = seg * 32;
    int l1 = l0 + 32; if (l1 > 2047) l1 = 2047;
    float sA = 0.f, sB = 0.f, sC = 0.f, T = 0.f, M = 0.f, U = 0.f;
    const float* base = u + ((size_t)b * LSEQ + l0) * 192 + c;
    for (int l = l0; l < l1; ++l) {
        float ua = base[0], ub = base[64], uc = base[128];
        base += 192;
        U += uc * T;
        M += uc * sB;
        T += ub * sA;
        sA += ua; sB += ub; sC += uc;
    }
    float* p = part + ((size_t)(b * 64 + seg)) * 384 + c;
    p[0] = sA; p[64] = sB; p[128] = sC; p[192] = T; p[256] = M; p[320] = U;
}

__global__ __launch_bounds__(64) void scan_combine_kernel(const float* __restrict__ part, float* __restrict__ s) {
    int b = blockIdx.x;
    int c = threadIdx.x;
    const float* p = part + (size_t)b * 64 * 384 + c;
    float A = p[0], B = p[64], Tt = p[192], Mt = p[256], Ut = p[320];
    for (int seg = 1; seg < 64; ++seg) {
        const float* q = p + seg * 384;
        float a2 = q[0], b2 = q[64], c2 = q[128], t2 = q[192], m2 = q[256], u2 = q[320];
        float Un = Ut + u2 + c2 * Tt + A * m2;
        float Tn = Tt + t2 + A * b2;
        float Mn = Mt + m2 + B * c2;
        A += a2; B += b2;
        Ut = Un; Tt = Tn; Mt = Mn;
    }
    s[b * 64 + c] = Ut;
}

// ------- final: LN(x[:, -1]) @ Wq + bq + s/denom -> fp32 out -------
__global__ __launch_bounds__(64) void final_kernel(const float* __restrict__ x,
        const float* __restrict__ s,
        const float* __restrict__ qw, const float* __restrict__ qb,
        const float* __restrict__ Wq, const float* __restrict__ bq,
        float* __restrict__ out, float inv_denom) {
    int b = blockIdx.x;
    int c = threadIdx.x;
    __shared__ float q[512];
    __shared__ float mv[2];
    const float* xr = x + ((size_t)b * LSEQ + (LSEQ - 1)) * 512;
    float s1 = 0.f, s2 = 0.f;
    for (int i = c; i < 512; i += 64) { float v = xr[i]; q[i] = v; s1 += v; s2 += v * v; }
    #pragma unroll
    for (int o = 32; o > 0; o >>= 1) { s1 += __shfl_down(s1, o); s2 += __shfl_down(s2, o); }
    if (c == 0) {
        float m = s1 * (1.0f / 512.0f);
        float var = s2 * (1.0f / 512.0f) - m * m;
        mv[0] = m; mv[1] = 1.0f / sqrtf(var + 1e-5f);
    }
    __syncthreads();
    float m = mv[0], r = mv[1];
    for (int i = c; i < 512; i += 64) q[i] = (q[i] - m) * r * qw[i] + qb[i];
    __syncthreads();
    float acc = 0.f;
    for (int d = 0; d < 512; ++d) acc += q[d] * Wq[d * 64 + c];
    out[b * 64 + c] = s[b * 64 + c] * inv_denom + acc + bq[c];
}

extern "C" void kernel_launch(void* const* d_in, const int* in_sizes, int n_in,
                              void* d_out, int out_size, void* d_ws, size_t ws_size,
                              hipStream_t stream) {
    const int*   token_ids   = (const int*)d_in[0];
    const float* tok_emb     = (const float*)d_in[1];
    const float* pos_emb     = (const float*)d_in[2];
    const float* stem_ln_w   = (const float*)d_in[3];
    const float* stem_ln_b   = (const float*)d_in[4];
    const float* stem_w1     = (const float*)d_in[5];
    const float* stem_b1     = (const float*)d_in[6];
    const float* stem_w2     = (const float*)d_in[7];
    const float* stem_b2     = (const float*)d_in[8];
    const float* role_ln_w   = (const float*)d_in[9];
    const float* role_ln_b   = (const float*)d_in[10];
    const float* Wa          = (const float*)d_in[11];
    const float* Wb          = (const float*)d_in[12];
    const float* Wc          = (const float*)d_in[13];
    const float* class_a     = (const float*)d_in[14];
    const float* class_b     = (const float*)d_in[15];
    const float* class_c     = (const float*)d_in[16];
    const float* query_ln_w  = (const float*)d_in[17];
    const float* query_ln_b  = (const float*)d_in[18];
    const float* Wq          = (const float*)d_in[19];
    const float* bq          = (const float*)d_in[20];
    float* out = (float*)d_out;

    // workspace layout (max 88,301,568 B — same footprint as the passing round)
    char* wsb = (char*)d_ws;
    float* x             = (float*)(wsb);                       // 33,554,432
    unsigned short* hl   = (unsigned short*)(wsb + 33554432);   // 16,777,216
    unsigned short* Hb   = (unsigned short*)(wsb + 50331648);   // 33,554,432 (stem phase)
    unsigned short* abc  = Hb;                                  // alias after stem: [3][16384][64] bf16 = 6,291,456
    float* uu            = (float*)(wsb + 58720256);            // [16384][192] fp32 = 12,582,912 (ends 71,303,168)
    float* part          = (float*)(wsb + 71303168);            // 786,432 (ends 72,089,600)
    float* svec          = (float*)(wsb + 72089600);            // 2,048
    unsigned short* w1T  = (unsigned short*)(wsb + 83886080);   // 2,097,152
    unsigned short* w2T  = (unsigned short*)(wsb + 85983232);   // 2,097,152
    unsigned short* wabcT= (unsigned short*)(wsb + 88080384);   // 196,608
    unsigned short* clsb = (unsigned short*)(wsb + 88276992);   // 24,576

    dim3 tb(32, 8);
    transpose_kernel<<<dim3(32, 16), tb, 0, stream>>>(stem_w1,          512, 1024, w1T,          512);
    transpose_kernel<<<dim3(32, 16), tb, 0, stream>>>(stem_w1 + 524288, 512, 1024, w1T + 524288, 512);
    transpose_kernel<<<dim3(16, 32), tb, 0, stream>>>(stem_w2,          1024, 512, w2T,          1024);
    transpose_kernel<<<dim3(16, 32), tb, 0, stream>>>(stem_w2 + 524288, 1024, 512, w2T + 524288, 1024);
    transpose_kernel<<<dim3(2, 16),  tb, 0, stream>>>(Wa, 512, 64, wabcT,         512);
    transpose_kernel<<<dim3(2, 16),  tb, 0, stream>>>(Wb, 512, 64, wabcT + 32768, 512);
    transpose_kernel<<<dim3(2, 16),  tb, 0, stream>>>(Wc, 512, 64, wabcT + 65536, 512);
    convert_kernel<<<16, 256, 0, stream>>>(class_a, clsb,        4096);
    convert_kernel<<<16, 256, 0, stream>>>(class_b, clsb + 4096, 4096);
    convert_kernel<<<16, 256, 0, stream>>>(class_c, clsb + 8192, 4096);

    embed_kernel<<<NROWS, 128, 0, stream>>>(token_ids, tok_emb, pos_emb, x);

    for (int i = 0; i < 2; ++i) {
        ln_kernel<<<NROWS, 256, 0, stream>>>(x, stem_ln_w + i * 512, stem_ln_b + i * 512, hl);
        gemm_kernel<EPI_GELU_BF16><<<dim3(128, 8), 256, 0, stream>>>(
            hl, 512, w1T + i * 524288, 512, stem_b1 + i * 1024, nullptr, Hb, 1024, 1024, 512, 0, 0, 0);
        gemm_kernel<EPI_RES_F32><<<dim3(128, 4), 256, 0, stream>>>(
            Hb, 1024, w2T + i * 524288, 1024, stem_b2 + i * 512, x, x, 512, 512, 1024, 0, 0, 0);
    }

    ln_kernel<<<NROWS, 256, 0, stream>>>(x, role_ln_w, role_ln_b, hl);
    gemm_kernel<EPI_TANH_SPLIT><<<dim3(128, 2), 256, 0, stream>>>(
        hl, 512, wabcT, 512, nullptr, nullptr, abc, 0, 192, 512, 0, 0, 0);

    // batched class GEMM: z selects group; A stride 16384*64, B stride 64*64, C col-offset 64
    gemm_kernel<EPI_F32><<<dim3(128, 1, 3), 256, 0, stream>>>(
        abc, 64, clsb, 64, nullptr, nullptr, uu, 192, 64, 64, 1048576, 4096, 64);

    scan_part_kernel<<<dim3(NB, 64), 64, 0, stream>>>(uu, part);
    scan_combine_kernel<<<NB, 64, 0, stream>>>(part, svec);

    float inv_denom = (float)(6.0 / (2047.0 * 2046.0 * 2045.0));
    final_kernel<<<NB, 64, 0, stream>>>(x, svec, query_ln_w, query_ln_b, Wq, bq, out, inv_denom);
}

// Round 4
// 400.714 us; speedup vs baseline: 1.1600x; 1.1180x over previous
//
#include <hip/hip_runtime.h>

#define NROWS 16384   // B*L
#define LSEQ  2048
#define NB    8

typedef short v8s __attribute__((ext_vector_type(8)));
typedef float v4f __attribute__((ext_vector_type(4)));

__device__ __forceinline__ unsigned short f2bf(float f) {
    unsigned int u = __float_as_uint(f);
    return (unsigned short)((u + 0x7fffu + ((u >> 16) & 1u)) >> 16);
}

// ------- tiled transpose + fp32->bf16: out[c*ldo + r] = bf16(in[r*C + c]) -------
__global__ void transpose_kernel(const float* __restrict__ in, int R, int C,
                                 unsigned short* __restrict__ out, int ldo) {
    __shared__ unsigned short tile[32][33];
    int c0 = blockIdx.x * 32, r0 = blockIdx.y * 32;
    int tx = threadIdx.x, ty = threadIdx.y;
    for (int i = ty; i < 32; i += 8) {
        int r = r0 + i, c = c0 + tx;
        tile[i][tx] = (r < R && c < C) ? f2bf(in[r * C + c]) : (unsigned short)0;
    }
    __syncthreads();
    for (int i = ty; i < 32; i += 8) {
        int c = c0 + i, r = r0 + tx;
        if (r < R && c < C) out[c * ldo + r] = tile[tx][i];
    }
}

__global__ void convert_kernel(const float* __restrict__ in, unsigned short* __restrict__ out, int n) {
    int i = blockIdx.x * 256 + threadIdx.x;
    if (i < n) out[i] = f2bf(in[i]);
}

// ------- fused embedding gather + pos add + LayerNorm0: writes x fp32 and hl bf16 -------
__global__ __launch_bounds__(256) void embed_ln_kernel(const int* __restrict__ ids,
        const float* __restrict__ tok, const float* __restrict__ pos,
        const float* __restrict__ g, const float* __restrict__ b,
        float* __restrict__ x, unsigned short* __restrict__ hl) {
    int row = blockIdx.x;
    int l = row & (LSEQ - 1);
    int t = threadIdx.x;
    int id = ids[row];
    float a0 = tok[(size_t)id * 512 + t]       + pos[(size_t)l * 512 + t];
    float a1 = tok[(size_t)id * 512 + t + 256] + pos[(size_t)l * 512 + t + 256];
    x[(size_t)row * 512 + t]       = a0;
    x[(size_t)row * 512 + t + 256] = a1;
    float s = a0 + a1, s2 = a0 * a0 + a1 * a1;
    #pragma unroll
    for (int o = 32; o > 0; o >>= 1) { s += __shfl_down(s, o); s2 += __shfl_down(s2, o); }
    __shared__ float ps[4], ps2[4], mv[2];
    int w = t >> 6;
    if ((t & 63) == 0) { ps[w] = s; ps2[w] = s2; }
    __syncthreads();
    if (t == 0) {
        float S = ps[0] + ps[1] + ps[2] + ps[3];
        float S2 = ps2[0] + ps2[1] + ps2[2] + ps2[3];
        float m = S * (1.0f / 512.0f);
        float var = S2 * (1.0f / 512.0f) - m * m;
        mv[0] = m; mv[1] = 1.0f / sqrtf(var + 1e-5f);
    }
    __syncthreads();
    float m = mv[0], r = mv[1];
    hl[(size_t)row * 512 + t]       = f2bf((a0 - m) * r * g[t]       + b[t]);
    hl[(size_t)row * 512 + t + 256] = f2bf((a1 - m) * r * g[t + 256] + b[t + 256]);
}

// ------- LayerNorm over D=512, fp32 in -> bf16 out -------
__global__ __launch_bounds__(256) void ln_kernel(const float* __restrict__ x,
        const float* __restrict__ g, const float* __restrict__ b,
        unsigned short* __restrict__ out) {
    int row = blockIdx.x;
    int t = threadIdx.x;
    const float* xr = x + (size_t)row * 512;
    float a0 = xr[t], a1 = xr[t + 256];
    float s = a0 + a1, s2 = a0 * a0 + a1 * a1;
    #pragma unroll
    for (int o = 32; o > 0; o >>= 1) { s += __shfl_down(s, o); s2 += __shfl_down(s2, o); }
    __shared__ float ps[4], ps2[4], mv[2];
    int w = t >> 6;
    if ((t & 63) == 0) { ps[w] = s; ps2[w] = s2; }
    __syncthreads();
    if (t == 0) {
        float S = ps[0] + ps[1] + ps[2] + ps[3];
        float S2 = ps2[0] + ps2[1] + ps2[2] + ps2[3];
        float m = S * (1.0f / 512.0f);
        float var = S2 * (1.0f / 512.0f) - m * m;
        mv[0] = m; mv[1] = 1.0f / sqrtf(var + 1e-5f);
    }
    __syncthreads();
    float m = mv[0], r = mv[1];
    out[(size_t)row * 512 + t]       = f2bf((a0 - m) * r * g[t]       + b[t]);
    out[(size_t)row * 512 + t + 256] = f2bf((a1 - m) * r * g[t + 256] + b[t + 256]);
}

// ------- MFMA GEMM: single-barrier double-buffered K-loop, VGPR staging, XOR swizzle -------
// LDS chunk layout: position (r, s) holds global chunk s ^ ((r>>1)&3); conflict-free R/W.
#define EPI_GELU_BF16  0
#define EPI_RES_F32    1

template <int EPI, int TN>
__global__ __launch_bounds__(256) void gemm_db(
        const unsigned short* __restrict__ A, int lda,
        const unsigned short* __restrict__ BT, int ldb,
        const float* __restrict__ bias,
        void* Cout, int ldc, int K) {
    constexpr int NJ = TN / 32;
    __shared__ unsigned short As[2][128 * 32] __attribute__((aligned(16)));
    __shared__ unsigned short Bs[2][TN * 32] __attribute__((aligned(16)));
    const int t = threadIdx.x;
    const int lane = t & 63, wave = t >> 6;
    const int quad = lane >> 4, l16 = lane & 15;
    const int wm = (wave >> 1) * 64, wn = (wave & 1) * (TN / 2);
    const long tileM = (long)blockIdx.x * 128, tileN = (long)blockIdx.y * TN;

    const int srow = t >> 2, scg = t & 3;
    const int spos = scg ^ ((srow >> 1) & 3);
    const int swz = quad ^ ((l16 >> 1) & 3);
    const int uoff = srow * 32 + spos * 8;

    const unsigned short* gA0 = A + (tileM + srow) * lda + scg * 8;
    const unsigned short* gA1 = gA0 + 64 * (long)lda;
    const unsigned short* gB0 = BT + (tileN + srow) * ldb + scg * 8;
    const unsigned short* gB1 = gB0 + 64 * (long)ldb;

    v4f acc[4][NJ] = {};
    uint4 a0, a1, b0, b1;

    // prologue: stage tile 0 into buffer 0
    a0 = *(const uint4*)gA0; a1 = *(const uint4*)gA1; gA0 += 32; gA1 += 32;
    b0 = *(const uint4*)gB0; gB0 += 32;
    if (TN == 128) { b1 = *(const uint4*)gB1; gB1 += 32; }
    *(uint4*)&As[0][uoff] = a0;
    *(uint4*)&As[0][uoff + 64 * 32] = a1;
    *(uint4*)&Bs[0][uoff] = b0;
    if (TN == 128) *(uint4*)&Bs[0][uoff + 64 * 32] = b1;

    const int nk = K >> 5;
    for (int kk = 0; kk < nk; ++kk) {
        const int p = kk & 1;
        const bool more = kk + 1 < nk;
        if (more) {   // prefetch next tile into registers (latency overlaps compute below)
            a0 = *(const uint4*)gA0; a1 = *(const uint4*)gA1; gA0 += 32; gA1 += 32;
            b0 = *(const uint4*)gB0; gB0 += 32;
            if (TN == 128) { b1 = *(const uint4*)gB1; gB1 += 32; }
        }
        __syncthreads();   // buf p writes visible; prior reads of buf 1-p complete
        v8s af[4], bfr[NJ];
        #pragma unroll
        for (int i = 0; i < 4; ++i) af[i] = *(const v8s*)&As[p][(wm + i * 16 + l16) * 32 + swz * 8];
        #pragma unroll
        for (int j = 0; j < NJ; ++j) bfr[j] = *(const v8s*)&Bs[p][(wn + j * 16 + l16) * 32 + swz * 8];
        #pragma unroll
        for (int i = 0; i < 4; ++i)
            #pragma unroll
            for (int j = 0; j < NJ; ++j)
                acc[i][j] = __builtin_amdgcn_mfma_f32_16x16x32_bf16(af[i], bfr[j], acc[i][j], 0, 0, 0);
        if (more) {
            *(uint4*)&As[1 - p][uoff] = a0;
            *(uint4*)&As[1 - p][uoff + 64 * 32] = a1;
            *(uint4*)&Bs[1 - p][uoff] = b0;
            if (TN == 128) *(uint4*)&Bs[1 - p][uoff + 64 * 32] = b1;
        }
    }

    // D layout: col = lane&15, row = quad*4 + reg
    #pragma unroll
    for (int i = 0; i < 4; ++i) {
        #pragma unroll
        for (int j = 0; j < NJ; ++j) {
            long col = tileN + wn + j * 16 + l16;
            #pragma unroll
            for (int r = 0; r < 4; ++r) {
                long row = tileM + wm + i * 16 + quad * 4 + r;
                float v = acc[i][j][r];
                if (EPI == EPI_GELU_BF16) {
                    v += bias[col];
                    v = 0.5f * v * (1.0f + erff(v * 0.70710678118654752f));
                    ((unsigned short*)Cout)[row * ldc + col] = f2bf(v);
                } else {
                    float* C = (float*)Cout;
                    v += bias[col] + C[row * ldc + col];   // residual in-place
                    C[row * ldc + col] = v;
                }
            }
        }
    }
}

// ------- fused tanh-GEMM + class-GEMM: uu[:, g*64+c] = (tanh(hl @ Wg)) @ class_g^T -------
__global__ __launch_bounds__(256) void tanh_class_kernel(
        const unsigned short* __restrict__ A,    // hl [16384][512]
        const unsigned short* __restrict__ WT,   // wabcT [3][64][512]
        const unsigned short* __restrict__ cls,  // clsb [3][64][64]
        float* __restrict__ uu) {
    __shared__ unsigned short As[2][128 * 32] __attribute__((aligned(16)));
    __shared__ unsigned short Bs[2][64 * 32] __attribute__((aligned(16)));
    __shared__ unsigned short P[128 * 72] __attribute__((aligned(16)));
    const int t = threadIdx.x;
    const int lane = t & 63, wave = t >> 6;
    const int quad = lane >> 4, l16 = lane & 15;
    const int wm = (wave >> 1) * 64, wn = (wave & 1) * 32;
    const long tileM = (long)blockIdx.x * 128;
    const int g = blockIdx.y;

    const int srow = t >> 2, scg = t & 3;
    const int spos = scg ^ ((srow >> 1) & 3);
    const int swz = quad ^ ((l16 >> 1) & 3);
    const int uoff = srow * 32 + spos * 8;

    const unsigned short* BT = WT + g * 32768;
    // preload class B-frags: cf[kstep][j], n = wn + j*16 + l16, k = kstep*32 + quad*8
    v8s cf[2][2];
    #pragma unroll
    for (int ks = 0; ks < 2; ++ks)
        #pragma unroll
        for (int j = 0; j < 2; ++j)
            cf[ks][j] = *(const v8s*)&cls[g * 4096 + (wn + j * 16 + l16) * 64 + ks * 32 + quad * 8];

    const unsigned short* gA0 = A + (tileM + srow) * 512 + scg * 8;
    const unsigned short* gA1 = gA0 + 64 * 512;
    const unsigned short* gB0 = BT + srow * 512 + scg * 8;

    v4f acc[4][2] = {};
    uint4 a0, a1, b0;
    a0 = *(const uint4*)gA0; a1 = *(const uint4*)gA1; gA0 += 32; gA1 += 32;
    b0 = *(const uint4*)gB0; gB0 += 32;
    *(uint4*)&As[0][uoff] = a0;
    *(uint4*)&As[0][uoff + 64 * 32] = a1;
    *(uint4*)&Bs[0][uoff] = b0;

    for (int kk = 0; kk < 16; ++kk) {
        const int p = kk & 1;
        const bool more = kk < 15;
        if (more) {
            a0 = *(const uint4*)gA0; a1 = *(const uint4*)gA1; gA0 += 32; gA1 += 32;
            b0 = *(const uint4*)gB0; gB0 += 32;
        }
        __syncthreads();
        v8s af[4], bfr[2];
        #pragma unroll
        for (int i = 0; i < 4; ++i) af[i] = *(const v8s*)&As[p][(wm + i * 16 + l16) * 32 + swz * 8];
        #pragma unroll
        for (int j = 0; j < 2; ++j) bfr[j] = *(const v8s*)&Bs[p][(wn + j * 16 + l16) * 32 + swz * 8];
        #pragma unroll
        for (int i = 0; i < 4; ++i)
            #pragma unroll
            for (int j = 0; j < 2; ++j)
                acc[i][j] = __builtin_amdgcn_mfma_f32_16x16x32_bf16(af[i], bfr[j], acc[i][j], 0, 0, 0);
        if (more) {
            *(uint4*)&As[1 - p][uoff] = a0;
            *(uint4*)&As[1 - p][uoff + 64 * 32] = a1;
            *(uint4*)&Bs[1 - p][uoff] = b0;
        }
    }

    // tanh -> P (bf16, stride 72 to dodge bank conflicts)
    #pragma unroll
    for (int i = 0; i < 4; ++i)
        #pragma unroll
        for (int j = 0; j < 2; ++j)
            #pragma unroll
            for (int r = 0; r < 4; ++r)
                P[(wm + i * 16 + quad * 4 + r) * 72 + wn + j * 16 + l16] = f2bf(tanhf(acc[i][j][r]));
    __syncthreads();

    // stage 2: out = P(128x64) @ class_g^T, K=64 (2 k-steps)
    v4f acc2[4][2] = {};
    #pragma unroll
    for (int ks = 0; ks < 2; ++ks) {
        v8s paf[4];
        #pragma unroll
        for (int i = 0; i < 4; ++i)
            paf[i] = *(const v8s*)&P[(wm + i * 16 + l16) * 72 + ks * 32 + quad * 8];
        #pragma unroll
        for (int i = 0; i < 4; ++i)
            #pragma unroll
            for (int j = 0; j < 2; ++j)
                acc2[i][j] = __builtin_amdgcn_mfma_f32_16x16x32_bf16(paf[i], cf[ks][j], acc2[i][j], 0, 0, 0);
    }

    #pragma unroll
    for (int i = 0; i < 4; ++i)
        #pragma unroll
        for (int j = 0; j < 2; ++j) {
            int col = wn + j * 16 + l16;
            #pragma unroll
            for (int r = 0; r < 4; ++r) {
                long row = tileM + wm + i * 16 + quad * 4 + r;
                uu[row * 192 + g * 64 + col] = acc2[i][j][r];
            }
        }
}

// ------- exact ordered-triplet scan, two-pass -------
__global__ __launch_bounds__(64) void scan_part_kernel(const float* __restrict__ u, float* __restrict__ part) {
    int b = blockIdx.x, seg = blockIdx.y;
    int c = threadIdx.x;
    int l0 = seg * 32;
    int l1 = l0 + 32; if (l1 > 2047) l1 = 2047;
    float sA = 0.f, sB = 0.f, sC = 0.f, T = 0.f, M = 0.f, U = 0.f;
    const float* base = u + ((size_t)b * LSEQ + l0) * 192 + c;
    for (int l = l0; l < l1; ++l) {
        float ua = base[0], ub = base[64], uc = base[128];
        base += 192;
        U += uc * T;
        M += uc * sB;
        T += ub * sA;
        sA += ua; sB += ub; sC += uc;
    }
    float* p = part + ((size_t)(b * 64 + seg)) * 384 + c;
    p[0] = sA; p[64] = sB; p[128] = sC; p[192] = T; p[256] = M; p[320] = U;
}

__global__ __launch_bounds__(64) void scan_combine_kernel(const float* __restrict__ part, float* __restrict__ s) {
    int b = blockIdx.x;
    int c = threadIdx.x;
    const float* p = part + (size_t)b * 64 * 384 + c;
    float A = p[0], B = p[64], Tt = p[192], Mt = p[256], Ut = p[320];
    for (int seg = 1; seg < 64; ++seg) {
        const float* q = p + seg * 384;
        float a2 = q[0], b2 = q[64], c2 = q[128], t2 = q[192], m2 = q[256], u2 = q[320];
        float Un = Ut + u2 + c2 * Tt + A * m2;
        float Tn = Tt + t2 + A * b2;
        float Mn = Mt + m2 + B * c2;
        A += a2; B += b2;
        Ut = Un; Tt = Tn; Mt = Mn;
    }
    s[b * 64 + c] = Ut;
}

// ------- final: LN(x[:, -1]) @ Wq + bq + s/denom -> fp32 out -------
__global__ __launch_bounds__(64) void final_kernel(const float* __restrict__ x,
        const float* __restrict__ s,
        const float* __restrict__ qw, const float* __restrict__ qb,
        const float* __restrict__ Wq, const float* __restrict__ bq,
        float* __restrict__ out, float inv_denom) {
    int b = blockIdx.x;
    int c = threadIdx.x;
    __shared__ float q[512];
    __shared__ float mv[2];
    const float* xr = x + ((size_t)b * LSEQ + (LSEQ - 1)) * 512;
    float s1 = 0.f, s2 = 0.f;
    for (int i = c; i < 512; i += 64) { float v = xr[i]; q[i] = v; s1 += v; s2 += v * v; }
    #pragma unroll
    for (int o = 32; o > 0; o >>= 1) { s1 += __shfl_down(s1, o); s2 += __shfl_down(s2, o); }
    if (c == 0) {
        float m = s1 * (1.0f / 512.0f);
        float var = s2 * (1.0f / 512.0f) - m * m;
        mv[0] = m; mv[1] = 1.0f / sqrtf(var + 1e-5f);
    }
    __syncthreads();
    float m = mv[0], r = mv[1];
    for (int i = c; i < 512; i += 64) q[i] = (q[i] - m) * r * qw[i] + qb[i];
    __syncthreads();
    float acc = 0.f;
    for (int d = 0; d < 512; ++d) acc += q[d] * Wq[d * 64 + c];
    out[b * 64 + c] = s[b * 64 + c] * inv_denom + acc + bq[c];
}

extern "C" void kernel_launch(void* const* d_in, const int* in_sizes, int n_in,
                              void* d_out, int out_size, void* d_ws, size_t ws_size,
                              hipStream_t stream) {
    const int*   token_ids   = (const int*)d_in[0];
    const float* tok_emb     = (const float*)d_in[1];
    const float* pos_emb     = (const float*)d_in[2];
    const float* stem_ln_w   = (const float*)d_in[3];
    const float* stem_ln_b   = (const float*)d_in[4];
    const float* stem_w1     = (const float*)d_in[5];
    const float* stem_b1     = (const float*)d_in[6];
    const float* stem_w2     = (const float*)d_in[7];
    const float* stem_b2     = (const float*)d_in[8];
    const float* role_ln_w   = (const float*)d_in[9];
    const float* role_ln_b   = (const float*)d_in[10];
    const float* Wa          = (const float*)d_in[11];
    const float* Wb          = (const float*)d_in[12];
    const float* Wc          = (const float*)d_in[13];
    const float* class_a     = (const float*)d_in[14];
    const float* class_b     = (const float*)d_in[15];
    const float* class_c     = (const float*)d_in[16];
    const float* query_ln_w  = (const float*)d_in[17];
    const float* query_ln_b  = (const float*)d_in[18];
    const float* Wq          = (const float*)d_in[19];
    const float* bq          = (const float*)d_in[20];
    float* out = (float*)d_out;

    // workspace layout (~88.3 MB)
    char* wsb = (char*)d_ws;
    float* x             = (float*)(wsb);                       // 33,554,432
    unsigned short* hl   = (unsigned short*)(wsb + 33554432);   // 16,777,216
    unsigned short* Hb   = (unsigned short*)(wsb + 50331648);   // 33,554,432 (stem phase)
    float* uu            = (float*)(wsb + 58720256);            // [16384][192] fp32 (Hb dead by then)
    float* part          = (float*)(wsb + 71303168);            // 786,432
    float* svec          = (float*)(wsb + 72089600);            // 2,048
    unsigned short* w1T  = (unsigned short*)(wsb + 83886080);   // 2,097,152
    unsigned short* w2T  = (unsigned short*)(wsb + 85983232);   // 2,097,152
    unsigned short* wabcT= (unsigned short*)(wsb + 88080384);   // 196,608
    unsigned short* clsb = (unsigned short*)(wsb + 88276992);   // 24,576

    dim3 tb(32, 8);
    transpose_kernel<<<dim3(32, 16), tb, 0, stream>>>(stem_w1,          512, 1024, w1T,          512);
    transpose_kernel<<<dim3(32, 16), tb, 0, stream>>>(stem_w1 + 524288, 512, 1024, w1T + 524288, 512);
    transpose_kernel<<<dim3(16, 32), tb, 0, stream>>>(stem_w2,          1024, 512, w2T,          1024);
    transpose_kernel<<<dim3(16, 32), tb, 0, stream>>>(stem_w2 + 524288, 1024, 512, w2T + 524288, 1024);
    transpose_kernel<<<dim3(2, 16),  tb, 0, stream>>>(Wa, 512, 64, wabcT,         512);
    transpose_kernel<<<dim3(2, 16),  tb, 0, stream>>>(Wb, 512, 64, wabcT + 32768, 512);
    transpose_kernel<<<dim3(2, 16),  tb, 0, stream>>>(Wc, 512, 64, wabcT + 65536, 512);
    convert_kernel<<<16, 256, 0, stream>>>(class_a, clsb,        4096);
    convert_kernel<<<16, 256, 0, stream>>>(class_b, clsb + 4096, 4096);
    convert_kernel<<<16, 256, 0, stream>>>(class_c, clsb + 8192, 4096);

    embed_ln_kernel<<<NROWS, 256, 0, stream>>>(token_ids, tok_emb, pos_emb,
                                               stem_ln_w, stem_ln_b, x, hl);

    for (int i = 0; i < 2; ++i) {
        if (i > 0)
            ln_kernel<<<NROWS, 256, 0, stream>>>(x, stem_ln_w + 512, stem_ln_b + 512, hl);
        gemm_db<EPI_GELU_BF16, 128><<<dim3(128, 8), 256, 0, stream>>>(
            hl, 512, w1T + i * 524288, 512, stem_b1 + i * 1024, Hb, 1024, 512);
        gemm_db<EPI_RES_F32, 64><<<dim3(128, 8), 256, 0, stream>>>(
            Hb, 1024, w2T + i * 524288, 1024, stem_b2 + i * 512, x, 512, 1024);
    }

    ln_kernel<<<NROWS, 256, 0, stream>>>(x, role_ln_w, role_ln_b, hl);

    tanh_class_kernel<<<dim3(128, 3), 256, 0, stream>>>(hl, wabcT, clsb, uu);

    scan_part_kernel<<<dim3(NB, 64), 64, 0, stream>>>(uu, part);
    scan_combine_kernel<<<NB, 64, 0, stream>>>(part, svec);

    float inv_denom = (float)(6.0 / (2047.0 * 2046.0 * 2045.0));
    final_kernel<<<NB, 64, 0, stream>>>(x, svec, query_ln_w, query_ln_b, Wq, bq, out, inv_denom);
}

// Round 5
// 354.817 us; speedup vs baseline: 1.3100x; 1.1294x over previous
//
#include <hip/hip_runtime.h>

#define NROWS 16384   // B*L
#define LSEQ  2048
#define NB    8

typedef short v8s __attribute__((ext_vector_type(8)));
typedef float v4f __attribute__((ext_vector_type(4)));

__device__ __forceinline__ unsigned short f2bf(float f) {
    unsigned int u = __float_as_uint(f);
    return (unsigned short)((u + 0x7fffu + ((u >> 16) & 1u)) >> 16);
}
__device__ __forceinline__ float bf2f(unsigned short u) {
    return __uint_as_float(((unsigned int)u) << 16);
}

// fast exact-GELU: Abramowitz-Stegun 5-term erf, |err|<1.5e-7, native exp/rcp
__device__ __forceinline__ float fast_gelu(float v) {
    float z = fabsf(v) * 0.70710678118654752f;
    float t = __builtin_amdgcn_rcpf(1.0f + 0.3275911f * z);
    float poly = t * (0.254829592f + t * (-0.284496736f + t * (1.421413741f +
                 t * (-1.453152027f + t * 1.061405429f))));
    float erfz = 1.0f - poly * __expf(-z * z);
    float er = copysignf(erfz, v);
    return 0.5f * v * (1.0f + er);
}
__device__ __forceinline__ float fast_tanh(float y) {
    float e = __expf(2.0f * y);
    return (e - 1.0f) * __builtin_amdgcn_rcpf(e + 1.0f);
}

// ------- one-shot prep: 4 big weight transposes + 3 small + 3 class converts -------
__global__ __launch_bounds__(256) void prep_kernel(
        const float* __restrict__ w1, const float* __restrict__ w2,
        const float* __restrict__ wa, const float* __restrict__ wb, const float* __restrict__ wc,
        const float* __restrict__ ca, const float* __restrict__ cb, const float* __restrict__ cc,
        unsigned short* __restrict__ w1T, unsigned short* __restrict__ w2T,
        unsigned short* __restrict__ wabcT, unsigned short* __restrict__ clsb) {
    int id = blockIdx.x;
    int tx = threadIdx.x, ty = threadIdx.y;
    if (id < 2144) {
        const float* in; unsigned short* out; int R, C, bx, by, ldo;
        if (id < 1024) {
            int l = id >> 9, r = id & 511;
            in = w1 + l * 524288; out = w1T + l * 524288;
            R = 512; C = 1024; bx = r & 31; by = r >> 5; ldo = 512;
        } else if (id < 2048) {
            int l = (id - 1024) >> 9, r = (id - 1024) & 511;
            in = w2 + l * 524288; out = w2T + l * 524288;
            R = 1024; C = 512; bx = r & 15; by = r >> 4; ldo = 1024;
        } else {
            int g = (id - 2048) >> 5, r = (id - 2048) & 31;
            in = (g == 0) ? wa : (g == 1) ? wb : wc;
            out = wabcT + g * 32768;
            R = 512; C = 64; bx = r & 1; by = r >> 1; ldo = 512;
        }
        __shared__ unsigned short tile[32][33];
        int c0 = bx * 32, r0 = by * 32;
        for (int i = ty; i < 32; i += 8) {
            int r = r0 + i, c = c0 + tx;
            tile[i][tx] = (r < R && c < C) ? f2bf(in[(size_t)r * C + c]) : (unsigned short)0;
        }
        __syncthreads();
        for (int i = ty; i < 32; i += 8) {
            int c = c0 + i, r = r0 + tx;
            if (r < R && c < C) out[(size_t)c * ldo + r] = tile[tx][i];
        }
    } else {
        int g = id - 2144;
        const float* src = (g == 0) ? ca : (g == 1) ? cb : cc;
        unsigned short* dst = clsb + g * 4096;
        int tid = ty * 32 + tx;
        for (int i = tid; i < 4096; i += 256) dst[i] = f2bf(src[i]);
    }
}

// ------- fused embed + pos + LayerNorm0: writes x (bf16) and hl (bf16) -------
__global__ __launch_bounds__(256) void embed_ln_kernel(const int* __restrict__ ids,
        const float* __restrict__ tok, const float* __restrict__ pos,
        const float* __restrict__ g, const float* __restrict__ b,
        unsigned short* __restrict__ x, unsigned short* __restrict__ hl) {
    int row = blockIdx.x;
    int l = row & (LSEQ - 1);
    int t = threadIdx.x;
    int id = ids[row];
    float2 tv = *(const float2*)(tok + (size_t)id * 512 + 2 * t);
    float2 pv = *(const float2*)(pos + (size_t)l * 512 + 2 * t);
    float a0 = tv.x + pv.x, a1 = tv.y + pv.y;
    unsigned int xp = (unsigned int)f2bf(a0) | ((unsigned int)f2bf(a1) << 16);
    *(unsigned int*)(x + (size_t)row * 512 + 2 * t) = xp;
    float s = a0 + a1, s2 = a0 * a0 + a1 * a1;
    #pragma unroll
    for (int o = 32; o > 0; o >>= 1) { s += __shfl_down(s, o); s2 += __shfl_down(s2, o); }
    __shared__ float ps[4], ps2[4], mv[2];
    int w = t >> 6;
    if ((t & 63) == 0) { ps[w] = s; ps2[w] = s2; }
    __syncthreads();
    if (t == 0) {
        float S = ps[0] + ps[1] + ps[2] + ps[3];
        float S2 = ps2[0] + ps2[1] + ps2[2] + ps2[3];
        float m = S * (1.0f / 512.0f);
        float var = S2 * (1.0f / 512.0f) - m * m;
        mv[0] = m; mv[1] = 1.0f / sqrtf(var + 1e-5f);
    }
    __syncthreads();
    float m = mv[0], r = mv[1];
    unsigned int hp = (unsigned int)f2bf((a0 - m) * r * g[2 * t] + b[2 * t])
                    | ((unsigned int)f2bf((a1 - m) * r * g[2 * t + 1] + b[2 * t + 1]) << 16);
    *(unsigned int*)(hl + (size_t)row * 512 + 2 * t) = hp;
}

// ------- LayerNorm over D=512, bf16 in -> bf16 out -------
__global__ __launch_bounds__(256) void ln_kernel(const unsigned short* __restrict__ x,
        const float* __restrict__ g, const float* __restrict__ b,
        unsigned short* __restrict__ out) {
    int row = blockIdx.x;
    int t = threadIdx.x;
    unsigned int xp = *(const unsigned int*)(x + (size_t)row * 512 + 2 * t);
    float a0 = bf2f((unsigned short)(xp & 0xffff)), a1 = bf2f((unsigned short)(xp >> 16));
    float s = a0 + a1, s2 = a0 * a0 + a1 * a1;
    #pragma unroll
    for (int o = 32; o > 0; o >>= 1) { s += __shfl_down(s, o); s2 += __shfl_down(s2, o); }
    __shared__ float ps[4], ps2[4], mv[2];
    int w = t >> 6;
    if ((t & 63) == 0) { ps[w] = s; ps2[w] = s2; }
    __syncthreads();
    if (t == 0) {
        float S = ps[0] + ps[1] + ps[2] + ps[3];
        float S2 = ps2[0] + ps2[1] + ps2[2] + ps2[3];
        float m = S * (1.0f / 512.0f);
        float var = S2 * (1.0f / 512.0f) - m * m;
        mv[0] = m; mv[1] = 1.0f / sqrtf(var + 1e-5f);
    }
    __syncthreads();
    float m = mv[0], r = mv[1];
    unsigned int hp = (unsigned int)f2bf((a0 - m) * r * g[2 * t] + b[2 * t])
                    | ((unsigned int)f2bf((a1 - m) * r * g[2 * t + 1] + b[2 * t + 1]) << 16);
    *(unsigned int*)(out + (size_t)row * 512 + 2 * t) = hp;
}

// ------- MFMA GEMM: R2-winning structure (2-barrier, single LDS buf, VGPR staging),
//         + early prefetch issue. LDS stride 40 (measured-best). -------
#define EPI_GELU_BF16  0
#define EPI_RES_BF16   1

template <int EPI, int TN>
__global__ __launch_bounds__(256) void gemm_r2(
        const unsigned short* __restrict__ A, int lda,
        const unsigned short* __restrict__ BT, int ldb,
        const float* __restrict__ bias,
        const unsigned short* __restrict__ xres,
        unsigned short* __restrict__ Cout, int ldc, int K) {
    constexpr int NJ = TN / 32;
    __shared__ unsigned short As[128][40] __attribute__((aligned(16)));
    __shared__ unsigned short Bs[TN][40] __attribute__((aligned(16)));
    const int t = threadIdx.x;
    const int lane = t & 63, wave = t >> 6;
    const int quad = lane >> 4, l16 = lane & 15;
    const int wm = (wave >> 1) * 64, wn = (wave & 1) * (TN / 2);
    const long tileM = (long)blockIdx.x * 128, tileN = (long)blockIdx.y * TN;
    const int arow = t >> 2, acol = (t & 3) * 8;

    const unsigned short* gA0 = A + (tileM + arow) * lda + acol;
    const unsigned short* gA1 = gA0 + 64 * (long)lda;
    const unsigned short* gB0 = BT + (tileN + arow) * ldb + acol;
    const unsigned short* gB1 = gB0 + 64 * (long)ldb;

    v4f acc[4][NJ] = {};
    uint4 a0, a1, b0, b1;

    // prologue: tile 0
    a0 = *(const uint4*)gA0; a1 = *(const uint4*)gA1; gA0 += 32; gA1 += 32;
    b0 = *(const uint4*)gB0; gB0 += 32;
    if (TN == 128) { b1 = *(const uint4*)gB1; gB1 += 32; }
    *(uint4*)&As[arow][acol] = a0;
    *(uint4*)&As[arow + 64][acol] = a1;
    *(uint4*)&Bs[arow][acol] = b0;
    if (TN == 128) *(uint4*)&Bs[arow + 64][acol] = b1;

    const int nk = K >> 5;
    for (int kk = 0; kk < nk; ++kk) {
        __syncthreads();                    // staging writes visible
        const bool more = kk + 1 < nk;
        if (more) {                         // issue next tile early; vmcnt wait is at the ds_write below
            a0 = *(const uint4*)gA0; a1 = *(const uint4*)gA1; gA0 += 32; gA1 += 32;
            b0 = *(const uint4*)gB0; gB0 += 32;
            if (TN == 128) { b1 = *(const uint4*)gB1; gB1 += 32; }
        }
        v8s af[4], bfr[NJ];
        #pragma unroll
        for (int i = 0; i < 4; ++i) af[i] = *(const v8s*)&As[wm + i * 16 + l16][quad * 8];
        #pragma unroll
        for (int j = 0; j < NJ; ++j) bfr[j] = *(const v8s*)&Bs[wn + j * 16 + l16][quad * 8];
        #pragma unroll
        for (int i = 0; i < 4; ++i)
            #pragma unroll
            for (int j = 0; j < NJ; ++j)
                acc[i][j] = __builtin_amdgcn_mfma_f32_16x16x32_bf16(af[i], bfr[j], acc[i][j], 0, 0, 0);
        __syncthreads();                    // frag reads done
        if (more) {
            *(uint4*)&As[arow][acol] = a0;
            *(uint4*)&As[arow + 64][acol] = a1;
            *(uint4*)&Bs[arow][acol] = b0;
            if (TN == 128) *(uint4*)&Bs[arow + 64][acol] = b1;
        }
    }

    // D layout: col = lane&15, row = quad*4 + reg
    #pragma unroll
    for (int i = 0; i < 4; ++i) {
        #pragma unroll
        for (int j = 0; j < NJ; ++j) {
            long col = tileN + wn + j * 16 + l16;
            #pragma unroll
            for (int r = 0; r < 4; ++r) {
                long row = tileM + wm + i * 16 + quad * 4 + r;
                float v = acc[i][j][r];
                if (EPI == EPI_GELU_BF16) {
                    v = fast_gelu(v + bias[col]);
                    Cout[row * ldc + col] = f2bf(v);
                } else {
                    v += bias[col] + bf2f(xres[row * ldc + col]);
                    Cout[row * ldc + col] = f2bf(v);
                }
            }
        }
    }
}

// ------- fused tanh-GEMM + class-GEMM: uu[:, g*64+c] = tanh(hl @ Wg) @ class_g^T (bf16 out) -------
__global__ __launch_bounds__(256) void tanh_class_kernel(
        const unsigned short* __restrict__ A,
        const unsigned short* __restrict__ WT,
        const unsigned short* __restrict__ cls,
        unsigned short* __restrict__ uu) {
    __shared__ unsigned short As[2][128 * 32] __attribute__((aligned(16)));
    __shared__ unsigned short Bs[2][64 * 32] __attribute__((aligned(16)));
    __shared__ unsigned short P[128 * 72] __attribute__((aligned(16)));
    const int t = threadIdx.x;
    const int lane = t & 63, wave = t >> 6;
    const int quad = lane >> 4, l16 = lane & 15;
    const int wm = (wave >> 1) * 64, wn = (wave & 1) * 32;
    const long tileM = (long)blockIdx.x * 128;
    const int g = blockIdx.y;

    const int srow = t >> 2, scg = t & 3;
    const int spos = scg ^ ((srow >> 1) & 3);
    const int swz = quad ^ ((l16 >> 1) & 3);
    const int uoff = srow * 32 + spos * 8;

    const unsigned short* BT = WT + g * 32768;
    v8s cf[2][2];
    #pragma unroll
    for (int ks = 0; ks < 2; ++ks)
        #pragma unroll
        for (int j = 0; j < 2; ++j)
            cf[ks][j] = *(const v8s*)&cls[g * 4096 + (wn + j * 16 + l16) * 64 + ks * 32 + quad * 8];

    const unsigned short* gA0 = A + (tileM + srow) * 512 + scg * 8;
    const unsigned short* gA1 = gA0 + 64 * 512;
    const unsigned short* gB0 = BT + srow * 512 + scg * 8;

    v4f acc[4][2] = {};
    uint4 a0, a1, b0;
    a0 = *(const uint4*)gA0; a1 = *(const uint4*)gA1; gA0 += 32; gA1 += 32;
    b0 = *(const uint4*)gB0; gB0 += 32;
    *(uint4*)&As[0][uoff] = a0;
    *(uint4*)&As[0][uoff + 64 * 32] = a1;
    *(uint4*)&Bs[0][uoff] = b0;

    for (int kk = 0; kk < 16; ++kk) {
        const int p = kk & 1;
        const bool more = kk < 15;
        if (more) {
            a0 = *(const uint4*)gA0; a1 = *(const uint4*)gA1; gA0 += 32; gA1 += 32;
            b0 = *(const uint4*)gB0; gB0 += 32;
        }
        __syncthreads();
        v8s af[4], bfr[2];
        #pragma unroll
        for (int i = 0; i < 4; ++i) af[i] = *(const v8s*)&As[p][(wm + i * 16 + l16) * 32 + swz * 8];
        #pragma unroll
        for (int j = 0; j < 2; ++j) bfr[j] = *(const v8s*)&Bs[p][(wn + j * 16 + l16) * 32 + swz * 8];
        #pragma unroll
        for (int i = 0; i < 4; ++i)
            #pragma unroll
            for (int j = 0; j < 2; ++j)
                acc[i][j] = __builtin_amdgcn_mfma_f32_16x16x32_bf16(af[i], bfr[j], acc[i][j], 0, 0, 0);
        if (more) {
            *(uint4*)&As[1 - p][uoff] = a0;
            *(uint4*)&As[1 - p][uoff + 64 * 32] = a1;
            *(uint4*)&Bs[1 - p][uoff] = b0;
        }
    }

    #pragma unroll
    for (int i = 0; i < 4; ++i)
        #pragma unroll
        for (int j = 0; j < 2; ++j)
            #pragma unroll
            for (int r = 0; r < 4; ++r)
                P[(wm + i * 16 + quad * 4 + r) * 72 + wn + j * 16 + l16] = f2bf(fast_tanh(acc[i][j][r]));
    __syncthreads();

    v4f acc2[4][2] = {};
    #pragma unroll
    for (int ks = 0; ks < 2; ++ks) {
        v8s paf[4];
        #pragma unroll
        for (int i = 0; i < 4; ++i)
            paf[i] = *(const v8s*)&P[(wm + i * 16 + l16) * 72 + ks * 32 + quad * 8];
        #pragma unroll
        for (int i = 0; i < 4; ++i)
            #pragma unroll
            for (int j = 0; j < 2; ++j)
                acc2[i][j] = __builtin_amdgcn_mfma_f32_16x16x32_bf16(paf[i], cf[ks][j], acc2[i][j], 0, 0, 0);
    }

    #pragma unroll
    for (int i = 0; i < 4; ++i)
        #pragma unroll
        for (int j = 0; j < 2; ++j) {
            int col = wn + j * 16 + l16;
            #pragma unroll
            for (int r = 0; r < 4; ++r) {
                long row = tileM + wm + i * 16 + quad * 4 + r;
                uu[row * 192 + g * 64 + col] = f2bf(acc2[i][j][r]);
            }
        }
}

// ------- exact ordered-triplet scan, two-pass (uu bf16) -------
__global__ __launch_bounds__(64) void scan_part_kernel(const unsigned short* __restrict__ u,
                                                       float* __restrict__ part) {
    int b = blockIdx.x, seg = blockIdx.y;
    int c = threadIdx.x;
    int l0 = seg * 32;
    int l1 = l0 + 32; if (l1 > 2047) l1 = 2047;
    float sA = 0.f, sB = 0.f, sC = 0.f, T = 0.f, M = 0.f, U = 0.f;
    const unsigned short* base = u + ((size_t)b * LSEQ + l0) * 192 + c;
    for (int l = l0; l < l1; ++l) {
        float ua = bf2f(base[0]), ub = bf2f(base[64]), uc = bf2f(base[128]);
        base += 192;
        U += uc * T;
        M += uc * sB;
        T += ub * sA;
        sA += ua; sB += ub; sC += uc;
    }
    float* p = part + ((size_t)(b * 64 + seg)) * 384 + c;
    p[0] = sA; p[64] = sB; p[128] = sC; p[192] = T; p[256] = M; p[320] = U;
}

__global__ __launch_bounds__(64) void scan_combine_kernel(const float* __restrict__ part,
                                                          float* __restrict__ s) {
    int b = blockIdx.x;
    int c = threadIdx.x;
    const float* p = part + (size_t)b * 64 * 384 + c;
    float A = p[0], B = p[64], Tt = p[192], Mt = p[256], Ut = p[320];
    for (int seg = 1; seg < 64; ++seg) {
        const float* q = p + seg * 384;
        float a2 = q[0], b2 = q[64], c2 = q[128], t2 = q[192], m2 = q[256], u2 = q[320];
        float Un = Ut + u2 + c2 * Tt + A * m2;
        float Tn = Tt + t2 + A * b2;
        float Mn = Mt + m2 + B * c2;
        A += a2; B += b2;
        Ut = Un; Tt = Tn; Mt = Mn;
    }
    s[b * 64 + c] = Ut;
}

// ------- final: LN(x[:, -1]) @ Wq + bq + s/denom -> fp32 out -------
__global__ __launch_bounds__(64) void final_kernel(const unsigned short* __restrict__ x,
        const float* __restrict__ s,
        const float* __restrict__ qw, const float* __restrict__ qb,
        const float* __restrict__ Wq, const float* __restrict__ bq,
        float* __restrict__ out, float inv_denom) {
    int b = blockIdx.x;
    int c = threadIdx.x;
    __shared__ float q[512];
    __shared__ float mv[2];
    const unsigned short* xr = x + ((size_t)b * LSEQ + (LSEQ - 1)) * 512;
    float s1 = 0.f, s2 = 0.f;
    for (int i = c; i < 512; i += 64) { float v = bf2f(xr[i]); q[i] = v; s1 += v; s2 += v * v; }
    #pragma unroll
    for (int o = 32; o > 0; o >>= 1) { s1 += __shfl_down(s1, o); s2 += __shfl_down(s2, o); }
    if (c == 0) {
        float m = s1 * (1.0f / 512.0f);
        float var = s2 * (1.0f / 512.0f) - m * m;
        mv[0] = m; mv[1] = 1.0f / sqrtf(var + 1e-5f);
    }
    __syncthreads();
    float m = mv[0], r = mv[1];
    for (int i = c; i < 512; i += 64) q[i] = (q[i] - m) * r * qw[i] + qb[i];
    __syncthreads();
    float acc = 0.f;
    for (int d = 0; d < 512; ++d) acc += q[d] * Wq[d * 64 + c];
    out[b * 64 + c] = s[b * 64 + c] * inv_denom + acc + bq[c];
}

extern "C" void kernel_launch(void* const* d_in, const int* in_sizes, int n_in,
                              void* d_out, int out_size, void* d_ws, size_t ws_size,
                              hipStream_t stream) {
    const int*   token_ids   = (const int*)d_in[0];
    const float* tok_emb     = (const float*)d_in[1];
    const float* pos_emb     = (const float*)d_in[2];
    const float* stem_ln_w   = (const float*)d_in[3];
    const float* stem_ln_b   = (const float*)d_in[4];
    const float* stem_w1     = (const float*)d_in[5];
    const float* stem_b1     = (const float*)d_in[6];
    const float* stem_w2     = (const float*)d_in[7];
    const float* stem_b2     = (const float*)d_in[8];
    const float* role_ln_w   = (const float*)d_in[9];
    const float* role_ln_b   = (const float*)d_in[10];
    const float* Wa          = (const float*)d_in[11];
    const float* Wb          = (const float*)d_in[12];
    const float* Wc          = (const float*)d_in[13];
    const float* class_a     = (const float*)d_in[14];
    const float* class_b     = (const float*)d_in[15];
    const float* class_c     = (const float*)d_in[16];
    const float* query_ln_w  = (const float*)d_in[17];
    const float* query_ln_b  = (const float*)d_in[18];
    const float* Wq          = (const float*)d_in[19];
    const float* bq          = (const float*)d_in[20];
    float* out = (float*)d_out;

    // workspace (~78.6 MB)
    char* wsb = (char*)d_ws;
    unsigned short* x    = (unsigned short*)(wsb);              // 16,777,216
    unsigned short* hl   = (unsigned short*)(wsb + 16777216);   // 16,777,216
    unsigned short* Hb   = (unsigned short*)(wsb + 33554432);   // 33,554,432 (ends 67,108,864)
    unsigned short* uu   = (unsigned short*)(wsb + 67108864);   // 6,291,456
    float* part          = (float*)(wsb + 73400320);            // 786,432
    float* svec          = (float*)(wsb + 74186752);            // 2,048
    unsigned short* w1T  = (unsigned short*)(wsb + 74188800);   // 2,097,152
    unsigned short* w2T  = (unsigned short*)(wsb + 76285952);   // 2,097,152
    unsigned short* wabcT= (unsigned short*)(wsb + 78383104);   // 196,608
    unsigned short* clsb = (unsigned short*)(wsb + 78579712);   // 24,576

    prep_kernel<<<2147, dim3(32, 8), 0, stream>>>(stem_w1, stem_w2, Wa, Wb, Wc,
        class_a, class_b, class_c, w1T, w2T, wabcT, clsb);

    embed_ln_kernel<<<NROWS, 256, 0, stream>>>(token_ids, tok_emb, pos_emb,
                                               stem_ln_w, stem_ln_b, x, hl);

    for (int i = 0; i < 2; ++i) {
        if (i > 0)
            ln_kernel<<<NROWS, 256, 0, stream>>>(x, stem_ln_w + 512, stem_ln_b + 512, hl);
        gemm_r2<EPI_GELU_BF16, 128><<<dim3(128, 8), 256, 0, stream>>>(
            hl, 512, w1T + i * 524288, 512, stem_b1 + i * 1024, nullptr, Hb, 1024, 512);
        gemm_r2<EPI_RES_BF16, 64><<<dim3(128, 8), 256, 0, stream>>>(
            Hb, 1024, w2T + i * 524288, 1024, stem_b2 + i * 512, x, x, 512, 1024);
    }

    ln_kernel<<<NROWS, 256, 0, stream>>>(x, role_ln_w, role_ln_b, hl);

    tanh_class_kernel<<<dim3(128, 3), 256, 0, stream>>>(hl, wabcT, clsb, uu);

    scan_part_kernel<<<dim3(NB, 64), 64, 0, stream>>>(uu, part);
    scan_combine_kernel<<<NB, 64, 0, stream>>>(part, svec);

    float inv_denom = (float)(6.0 / (2047.0 * 2046.0 * 2045.0));
    final_kernel<<<NB, 64, 0, stream>>>(x, svec, query_ln_w, query_ln_b, Wq, bq, out, inv_denom);
}

// Round 6
// 351.040 us; speedup vs baseline: 1.3241x; 1.0108x over previous
//
#include <hip/hip_runtime.h>

#define NROWS 16384   // B*L
#define LSEQ  2048
#define NB    8

typedef short v8s __attribute__((ext_vector_type(8)));
typedef float v4f __attribute__((ext_vector_type(4)));

__device__ __forceinline__ unsigned short f2bf(float f) {
    unsigned int u = __float_as_uint(f);
    return (unsigned short)((u + 0x7fffu + ((u >> 16) & 1u)) >> 16);
}
__device__ __forceinline__ float bf2f(unsigned short u) {
    return __uint_as_float(((unsigned int)u) << 16);
}

// fast exact-GELU: Abramowitz-Stegun 5-term erf, |err|<1.5e-7
__device__ __forceinline__ float fast_gelu(float v) {
    float z = fabsf(v) * 0.70710678118654752f;
    float t = __builtin_amdgcn_rcpf(1.0f + 0.3275911f * z);
    float poly = t * (0.254829592f + t * (-0.284496736f + t * (1.421413741f +
                 t * (-1.453152027f + t * 1.061405429f))));
    float erfz = 1.0f - poly * __expf(-z * z);
    float er = copysignf(erfz, v);
    return 0.5f * v * (1.0f + er);
}
__device__ __forceinline__ float fast_tanh(float y) {
    float e = __expf(2.0f * y);
    return (e - 1.0f) * __builtin_amdgcn_rcpf(e + 1.0f);
}

// ------- one-shot prep: weight transposes + class converts -------
__global__ __launch_bounds__(256) void prep_kernel(
        const float* __restrict__ w1, const float* __restrict__ w2,
        const float* __restrict__ wa, const float* __restrict__ wb, const float* __restrict__ wc,
        const float* __restrict__ ca, const float* __restrict__ cb, const float* __restrict__ cc,
        unsigned short* __restrict__ w1T, unsigned short* __restrict__ w2T,
        unsigned short* __restrict__ wabcT, unsigned short* __restrict__ clsb) {
    int id = blockIdx.x;
    int tx = threadIdx.x, ty = threadIdx.y;
    if (id < 2144) {
        const float* in; unsigned short* out; int R, C, bx, by, ldo;
        if (id < 1024) {
            int l = id >> 9, r = id & 511;
            in = w1 + l * 524288; out = w1T + l * 524288;
            R = 512; C = 1024; bx = r & 31; by = r >> 5; ldo = 512;
        } else if (id < 2048) {
            int l = (id - 1024) >> 9, r = (id - 1024) & 511;
            in = w2 + l * 524288; out = w2T + l * 524288;
            R = 1024; C = 512; bx = r & 15; by = r >> 4; ldo = 1024;
        } else {
            int g = (id - 2048) >> 5, r = (id - 2048) & 31;
            in = (g == 0) ? wa : (g == 1) ? wb : wc;
            out = wabcT + g * 32768;
            R = 512; C = 64; bx = r & 1; by = r >> 1; ldo = 512;
        }
        __shared__ unsigned short tile[32][33];
        int c0 = bx * 32, r0 = by * 32;
        for (int i = ty; i < 32; i += 8) {
            int r = r0 + i, c = c0 + tx;
            tile[i][tx] = (r < R && c < C) ? f2bf(in[(size_t)r * C + c]) : (unsigned short)0;
        }
        __syncthreads();
        for (int i = ty; i < 32; i += 8) {
            int c = c0 + i, r = r0 + tx;
            if (r < R && c < C) out[(size_t)c * ldo + r] = tile[tx][i];
        }
    } else {
        int g = id - 2144;
        const float* src = (g == 0) ? ca : (g == 1) ? cb : cc;
        unsigned short* dst = clsb + g * 4096;
        int tid = ty * 32 + tx;
        for (int i = tid; i < 4096; i += 256) dst[i] = f2bf(src[i]);
    }
}

// ------- fused embed + pos + LN0: one wave per row, no barriers -------
__global__ __launch_bounds__(256) void embed_ln_kernel(const int* __restrict__ ids,
        const float* __restrict__ tok, const float* __restrict__ pos,
        const float* __restrict__ g, const float* __restrict__ b,
        unsigned short* __restrict__ x, unsigned short* __restrict__ hl) {
    int wave = threadIdx.x >> 6, lane = threadIdx.x & 63;
    long row = (long)blockIdx.x * 4 + wave;
    int l = (int)(row & (LSEQ - 1));
    int id = ids[row];
    int d = lane * 8;
    float4 t0 = *(const float4*)(tok + (size_t)id * 512 + d);
    float4 t1 = *(const float4*)(tok + (size_t)id * 512 + d + 4);
    float4 p0 = *(const float4*)(pos + (size_t)l * 512 + d);
    float4 p1 = *(const float4*)(pos + (size_t)l * 512 + d + 4);
    float a[8] = {t0.x + p0.x, t0.y + p0.y, t0.z + p0.z, t0.w + p0.w,
                  t1.x + p1.x, t1.y + p1.y, t1.z + p1.z, t1.w + p1.w};
    unsigned int xp[4];
    #pragma unroll
    for (int i = 0; i < 4; ++i)
        xp[i] = (unsigned int)f2bf(a[2 * i]) | ((unsigned int)f2bf(a[2 * i + 1]) << 16);
    *(uint4*)(x + row * 512 + d) = *(uint4*)xp;
    float s = 0.f, s2 = 0.f;
    #pragma unroll
    for (int i = 0; i < 8; ++i) { s += a[i]; s2 += a[i] * a[i]; }
    #pragma unroll
    for (int o = 32; o > 0; o >>= 1) { s += __shfl_down(s, o); s2 += __shfl_down(s2, o); }
    s = __shfl(s, 0); s2 = __shfl(s2, 0);
    float m = s * (1.0f / 512.0f);
    float rinv = 1.0f / sqrtf(s2 * (1.0f / 512.0f) - m * m + 1e-5f);
    float4 g0 = *(const float4*)(g + d), g1 = *(const float4*)(g + d + 4);
    float4 b0 = *(const float4*)(b + d), b1 = *(const float4*)(b + d + 4);
    float gg[8] = {g0.x, g0.y, g0.z, g0.w, g1.x, g1.y, g1.z, g1.w};
    float bb[8] = {b0.x, b0.y, b0.z, b0.w, b1.x, b1.y, b1.z, b1.w};
    unsigned int hp[4];
    #pragma unroll
    for (int i = 0; i < 4; ++i) {
        unsigned short lo = f2bf((a[2 * i]     - m) * rinv * gg[2 * i]     + bb[2 * i]);
        unsigned short hi = f2bf((a[2 * i + 1] - m) * rinv * gg[2 * i + 1] + bb[2 * i + 1]);
        hp[i] = (unsigned int)lo | ((unsigned int)hi << 16);
    }
    *(uint4*)(hl + row * 512 + d) = *(uint4*)hp;
}

// ------- LayerNorm, one wave per row -------
__global__ __launch_bounds__(256) void ln_kernel(const unsigned short* __restrict__ x,
        const float* __restrict__ g, const float* __restrict__ b,
        unsigned short* __restrict__ out) {
    int wave = threadIdx.x >> 6, lane = threadIdx.x & 63;
    long row = (long)blockIdx.x * 4 + wave;
    int d = lane * 8;
    uint4 xp = *(const uint4*)(x + row * 512 + d);
    const unsigned int* xw = (const unsigned int*)&xp;
    float a[8];
    #pragma unroll
    for (int i = 0; i < 4; ++i) {
        a[2 * i]     = bf2f((unsigned short)(xw[i] & 0xffff));
        a[2 * i + 1] = bf2f((unsigned short)(xw[i] >> 16));
    }
    float s = 0.f, s2 = 0.f;
    #pragma unroll
    for (int i = 0; i < 8; ++i) { s += a[i]; s2 += a[i] * a[i]; }
    #pragma unroll
    for (int o = 32; o > 0; o >>= 1) { s += __shfl_down(s, o); s2 += __shfl_down(s2, o); }
    s = __shfl(s, 0); s2 = __shfl(s2, 0);
    float m = s * (1.0f / 512.0f);
    float rinv = 1.0f / sqrtf(s2 * (1.0f / 512.0f) - m * m + 1e-5f);
    float4 g0 = *(const float4*)(g + d), g1 = *(const float4*)(g + d + 4);
    float4 b0 = *(const float4*)(b + d), b1 = *(const float4*)(b + d + 4);
    float gg[8] = {g0.x, g0.y, g0.z, g0.w, g1.x, g1.y, g1.z, g1.w};
    float bb[8] = {b0.x, b0.y, b0.z, b0.w, b1.x, b1.y, b1.z, b1.w};
    unsigned int hp[4];
    #pragma unroll
    for (int i = 0; i < 4; ++i) {
        unsigned short lo = f2bf((a[2 * i]     - m) * rinv * gg[2 * i]     + bb[2 * i]);
        unsigned short hi = f2bf((a[2 * i + 1] - m) * rinv * gg[2 * i + 1] + bb[2 * i + 1]);
        hp[i] = (unsigned int)lo | ((unsigned int)hi << 16);
    }
    *(uint4*)(out + row * 512 + d) = *(uint4*)hp;
}

// ------- MFMA GEMM: R2 2-barrier structure + swapped-operand packed epilogue -------
// mfma(bfr, af): per lane m = wm+i*16+l16 fixed, n = wn+j*16+quad*4+reg → ushort4 stores.
#define EPI_GELU_BF16  0
#define EPI_RES_BF16   1

template <int EPI, int TN>
__global__ __launch_bounds__(256) void gemm_r2(
        const unsigned short* __restrict__ A, int lda,
        const unsigned short* __restrict__ BT, int ldb,
        const float* __restrict__ bias,
        const unsigned short* __restrict__ xres,
        unsigned short* __restrict__ Cout, int ldc, int K) {
    constexpr int NJ = TN / 32;
    __shared__ unsigned short As[128][40] __attribute__((aligned(16)));
    __shared__ unsigned short Bs[TN][40] __attribute__((aligned(16)));
    const int t = threadIdx.x;
    const int lane = t & 63, wave = t >> 6;
    const int quad = lane >> 4, l16 = lane & 15;
    const int wm = (wave >> 1) * 64, wn = (wave & 1) * (TN / 2);
    const long tileM = (long)blockIdx.x * 128, tileN = (long)blockIdx.y * TN;
    const int arow = t >> 2, acol = (t & 3) * 8;

    const unsigned short* gA0 = A + (tileM + arow) * lda + acol;
    const unsigned short* gA1 = gA0 + 64 * (long)lda;
    const unsigned short* gB0 = BT + (tileN + arow) * ldb + acol;
    const unsigned short* gB1 = gB0 + 64 * (long)ldb;

    v4f acc[4][NJ] = {};
    uint4 a0, a1, b0, b1;

    a0 = *(const uint4*)gA0; a1 = *(const uint4*)gA1; gA0 += 32; gA1 += 32;
    b0 = *(const uint4*)gB0; gB0 += 32;
    if (TN == 128) { b1 = *(const uint4*)gB1; gB1 += 32; }
    *(uint4*)&As[arow][acol] = a0;
    *(uint4*)&As[arow + 64][acol] = a1;
    *(uint4*)&Bs[arow][acol] = b0;
    if (TN == 128) *(uint4*)&Bs[arow + 64][acol] = b1;

    const int nk = K >> 5;
    for (int kk = 0; kk < nk; ++kk) {
        __syncthreads();
        const bool more = kk + 1 < nk;
        if (more) {
            a0 = *(const uint4*)gA0; a1 = *(const uint4*)gA1; gA0 += 32; gA1 += 32;
            b0 = *(const uint4*)gB0; gB0 += 32;
            if (TN == 128) { b1 = *(const uint4*)gB1; gB1 += 32; }
        }
        v8s af[4], bfr[NJ];
        #pragma unroll
        for (int i = 0; i < 4; ++i) af[i] = *(const v8s*)&As[wm + i * 16 + l16][quad * 8];
        #pragma unroll
        for (int j = 0; j < NJ; ++j) bfr[j] = *(const v8s*)&Bs[wn + j * 16 + l16][quad * 8];
        #pragma unroll
        for (int i = 0; i < 4; ++i)
            #pragma unroll
            for (int j = 0; j < NJ; ++j)
                acc[i][j] = __builtin_amdgcn_mfma_f32_16x16x32_bf16(bfr[j], af[i], acc[i][j], 0, 0, 0);
        __syncthreads();
        if (more) {
            *(uint4*)&As[arow][acol] = a0;
            *(uint4*)&As[arow + 64][acol] = a1;
            *(uint4*)&Bs[arow][acol] = b0;
            if (TN == 128) *(uint4*)&Bs[arow + 64][acol] = b1;
        }
    }

    // packed epilogue: fixed m per lane, 4 consecutive n per acc
    #pragma unroll
    for (int i = 0; i < 4; ++i) {
        long m = tileM + wm + i * 16 + l16;
        #pragma unroll
        for (int j = 0; j < NJ; ++j) {
            long n0 = tileN + wn + j * 16 + quad * 4;
            float4 bi = *(const float4*)&bias[n0];
            const float* bip = (const float*)&bi;
            unsigned short pk[4];
            if (EPI == EPI_GELU_BF16) {
                #pragma unroll
                for (int r = 0; r < 4; ++r)
                    pk[r] = f2bf(fast_gelu(acc[i][j][r] + bip[r]));
            } else {
                ushort4 xr4 = *(const ushort4*)&xres[m * ldc + n0];
                const unsigned short* xp = (const unsigned short*)&xr4;
                #pragma unroll
                for (int r = 0; r < 4; ++r)
                    pk[r] = f2bf(acc[i][j][r] + bip[r] + bf2f(xp[r]));
            }
            *(ushort4*)&Cout[m * ldc + n0] = *(ushort4*)pk;
        }
    }
}

// ------- fused tanh-GEMM + class-GEMM (swapped-operand both stages) -------
__global__ __launch_bounds__(256) void tanh_class_kernel(
        const unsigned short* __restrict__ A,
        const unsigned short* __restrict__ WT,
        const unsigned short* __restrict__ cls,
        unsigned short* __restrict__ uu) {
    __shared__ unsigned short As[2][128 * 32] __attribute__((aligned(16)));
    __shared__ unsigned short Bs[2][64 * 32] __attribute__((aligned(16)));
    __shared__ unsigned short P[128 * 72] __attribute__((aligned(16)));
    const int t = threadIdx.x;
    const int lane = t & 63, wave = t >> 6;
    const int quad = lane >> 4, l16 = lane & 15;
    const int wm = (wave >> 1) * 64, wn = (wave & 1) * 32;
    const long tileM = (long)blockIdx.x * 128;
    const int g = blockIdx.y;

    const int srow = t >> 2, scg = t & 3;
    const int spos = scg ^ ((srow >> 1) & 3);
    const int swz = quad ^ ((l16 >> 1) & 3);
    const int uoff = srow * 32 + spos * 8;

    const unsigned short* BT = WT + g * 32768;
    v8s cf[2][2];
    #pragma unroll
    for (int ks = 0; ks < 2; ++ks)
        #pragma unroll
        for (int j = 0; j < 2; ++j)
            cf[ks][j] = *(const v8s*)&cls[g * 4096 + (wn + j * 16 + l16) * 64 + ks * 32 + quad * 8];

    const unsigned short* gA0 = A + (tileM + srow) * 512 + scg * 8;
    const unsigned short* gA1 = gA0 + 64 * 512;
    const unsigned short* gB0 = BT + srow * 512 + scg * 8;

    v4f acc[4][2] = {};
    uint4 a0, a1, b0;
    a0 = *(const uint4*)gA0; a1 = *(const uint4*)gA1; gA0 += 32; gA1 += 32;
    b0 = *(const uint4*)gB0; gB0 += 32;
    *(uint4*)&As[0][uoff] = a0;
    *(uint4*)&As[0][uoff + 64 * 32] = a1;
    *(uint4*)&Bs[0][uoff] = b0;

    for (int kk = 0; kk < 16; ++kk) {
        const int p = kk & 1;
        const bool more = kk < 15;
        if (more) {
            a0 = *(const uint4*)gA0; a1 = *(const uint4*)gA1; gA0 += 32; gA1 += 32;
            b0 = *(const uint4*)gB0; gB0 += 32;
        }
        __syncthreads();
        v8s af[4], bfr[2];
        #pragma unroll
        for (int i = 0; i < 4; ++i) af[i] = *(const v8s*)&As[p][(wm + i * 16 + l16) * 32 + swz * 8];
        #pragma unroll
        for (int j = 0; j < 2; ++j) bfr[j] = *(const v8s*)&Bs[p][(wn + j * 16 + l16) * 32 + swz * 8];
        #pragma unroll
        for (int i = 0; i < 4; ++i)
            #pragma unroll
            for (int j = 0; j < 2; ++j)
                acc[i][j] = __builtin_amdgcn_mfma_f32_16x16x32_bf16(bfr[j], af[i], acc[i][j], 0, 0, 0);
        if (more) {
            *(uint4*)&As[1 - p][uoff] = a0;
            *(uint4*)&As[1 - p][uoff + 64 * 32] = a1;
            *(uint4*)&Bs[1 - p][uoff] = b0;
        }
    }

    // P[m][n] packed ds_write_b64: per lane m fixed, n0 = wn+j*16+quad*4
    #pragma unroll
    for (int i = 0; i < 4; ++i) {
        int m = wm + i * 16 + l16;
        #pragma unroll
        for (int j = 0; j < 2; ++j) {
            int n0 = wn + j * 16 + quad * 4;
            unsigned short pk[4];
            #pragma unroll
            for (int r = 0; r < 4; ++r) pk[r] = f2bf(fast_tanh(acc[i][j][r]));
            *(ushort4*)&P[m * 72 + n0] = *(ushort4*)pk;
        }
    }
    __syncthreads();

    v4f acc2[4][2] = {};
    #pragma unroll
    for (int ks = 0; ks < 2; ++ks) {
        v8s paf[4];
        #pragma unroll
        for (int i = 0; i < 4; ++i)
            paf[i] = *(const v8s*)&P[(wm + i * 16 + l16) * 72 + ks * 32 + quad * 8];
        #pragma unroll
        for (int i = 0; i < 4; ++i)
            #pragma unroll
            for (int j = 0; j < 2; ++j)
                acc2[i][j] = __builtin_amdgcn_mfma_f32_16x16x32_bf16(cf[ks][j], paf[i], acc2[i][j], 0, 0, 0);
    }

    #pragma unroll
    for (int i = 0; i < 4; ++i) {
        long m = tileM + wm + i * 16 + l16;
        #pragma unroll
        for (int j = 0; j < 2; ++j) {
            int c0 = wn + j * 16 + quad * 4;
            unsigned short pk[4];
            #pragma unroll
            for (int r = 0; r < 4; ++r) pk[r] = f2bf(acc2[i][j][r]);
            *(ushort4*)&uu[m * 192 + g * 64 + c0] = *(ushort4*)pk;
        }
    }
}

// ------- exact ordered-triplet scan, two-pass (uu bf16) -------
__global__ __launch_bounds__(64) void scan_part_kernel(const unsigned short* __restrict__ u,
                                                       float* __restrict__ part) {
    int b = blockIdx.x, seg = blockIdx.y;
    int c = threadIdx.x;
    int l0 = seg * 32;
    int l1 = l0 + 32; if (l1 > 2047) l1 = 2047;
    float sA = 0.f, sB = 0.f, sC = 0.f, T = 0.f, M = 0.f, U = 0.f;
    const unsigned short* base = u + ((size_t)b * LSEQ + l0) * 192 + c;
    for (int l = l0; l < l1; ++l) {
        float ua = bf2f(base[0]), ub = bf2f(base[64]), uc = bf2f(base[128]);
        base += 192;
        U += uc * T;
        M += uc * sB;
        T += ub * sA;
        sA += ua; sB += ub; sC += uc;
    }
    float* p = part + ((size_t)(b * 64 + seg)) * 384 + c;
    p[0] = sA; p[64] = sB; p[128] = sC; p[192] = T; p[256] = M; p[320] = U;
}

__global__ __launch_bounds__(64) void scan_combine_kernel(const float* __restrict__ part,
                                                          float* __restrict__ s) {
    int b = blockIdx.x;
    int c = threadIdx.x;
    const float* p = part + (size_t)b * 64 * 384 + c;
    float A = p[0], B = p[64], Tt = p[192], Mt = p[256], Ut = p[320];
    for (int seg = 1; seg < 64; ++seg) {
        const float* q = p + seg * 384;
        float a2 = q[0], b2 = q[64], c2 = q[128], t2 = q[192], m2 = q[256], u2 = q[320];
        float Un = Ut + u2 + c2 * Tt + A * m2;
        float Tn = Tt + t2 + A * b2;
        float Mn = Mt + m2 + B * c2;
        A += a2; B += b2;
        Ut = Un; Tt = Tn; Mt = Mn;
    }
    s[b * 64 + c] = Ut;
}

// ------- final: LN(x[:, -1]) @ Wq + bq + s/denom -> fp32 out -------
__global__ __launch_bounds__(64) void final_kernel(const unsigned short* __restrict__ x,
        const float* __restrict__ s,
        const float* __restrict__ qw, const float* __restrict__ qb,
        const float* __restrict__ Wq, const float* __restrict__ bq,
        float* __restrict__ out, float inv_denom) {
    int b = blockIdx.x;
    int c = threadIdx.x;
    __shared__ float q[512];
    __shared__ float mv[2];
    const unsigned short* xr = x + ((size_t)b * LSEQ + (LSEQ - 1)) * 512;
    float s1 = 0.f, s2 = 0.f;
    for (int i = c; i < 512; i += 64) { float v = bf2f(xr[i]); q[i] = v; s1 += v; s2 += v * v; }
    #pragma unroll
    for (int o = 32; o > 0; o >>= 1) { s1 += __shfl_down(s1, o); s2 += __shfl_down(s2, o); }
    if (c == 0) {
        float m = s1 * (1.0f / 512.0f);
        float var = s2 * (1.0f / 512.0f) - m * m;
        mv[0] = m; mv[1] = 1.0f / sqrtf(var + 1e-5f);
    }
    __syncthreads();
    float m = mv[0], r = mv[1];
    for (int i = c; i < 512; i += 64) q[i] = (q[i] - m) * r * qw[i] + qb[i];
    __syncthreads();
    float acc = 0.f;
    for (int d = 0; d < 512; ++d) acc += q[d] * Wq[d * 64 + c];
    out[b * 64 + c] = s[b * 64 + c] * inv_denom + acc + bq[c];
}

extern "C" void kernel_launch(void* const* d_in, const int* in_sizes, int n_in,
                              void* d_out, int out_size, void* d_ws, size_t ws_size,
                              hipStream_t stream) {
    const int*   token_ids   = (const int*)d_in[0];
    const float* tok_emb     = (const float*)d_in[1];
    const float* pos_emb     = (const float*)d_in[2];
    const float* stem_ln_w   = (const float*)d_in[3];
    const float* stem_ln_b   = (const float*)d_in[4];
    const float* stem_w1     = (const float*)d_in[5];
    const float* stem_b1     = (const float*)d_in[6];
    const float* stem_w2     = (const float*)d_in[7];
    const float* stem_b2     = (const float*)d_in[8];
    const float* role_ln_w   = (const float*)d_in[9];
    const float* role_ln_b   = (const float*)d_in[10];
    const float* Wa          = (const float*)d_in[11];
    const float* Wb          = (const float*)d_in[12];
    const float* Wc          = (const float*)d_in[13];
    const float* class_a     = (const float*)d_in[14];
    const float* class_b     = (const float*)d_in[15];
    const float* class_c     = (const float*)d_in[16];
    const float* query_ln_w  = (const float*)d_in[17];
    const float* query_ln_b  = (const float*)d_in[18];
    const float* Wq          = (const float*)d_in[19];
    const float* bq          = (const float*)d_in[20];
    float* out = (float*)d_out;

    char* wsb = (char*)d_ws;
    unsigned short* x    = (unsigned short*)(wsb);              // 16,777,216
    unsigned short* hl   = (unsigned short*)(wsb + 16777216);   // 16,777,216
    unsigned short* Hb   = (unsigned short*)(wsb + 33554432);   // 33,554,432
    unsigned short* uu   = (unsigned short*)(wsb + 67108864);   // 6,291,456
    float* part          = (float*)(wsb + 73400320);            // 786,432
    float* svec          = (float*)(wsb + 74186752);            // 2,048
    unsigned short* w1T  = (unsigned short*)(wsb + 74188800);   // 2,097,152
    unsigned short* w2T  = (unsigned short*)(wsb + 76285952);   // 2,097,152
    unsigned short* wabcT= (unsigned short*)(wsb + 78383104);   // 196,608
    unsigned short* clsb = (unsigned short*)(wsb + 78579712);   // 24,576

    prep_kernel<<<2147, dim3(32, 8), 0, stream>>>(stem_w1, stem_w2, Wa, Wb, Wc,
        class_a, class_b, class_c, w1T, w2T, wabcT, clsb);

    embed_ln_kernel<<<NROWS / 4, 256, 0, stream>>>(token_ids, tok_emb, pos_emb,
                                                   stem_ln_w, stem_ln_b, x, hl);

    for (int i = 0; i < 2; ++i) {
        if (i > 0)
            ln_kernel<<<NROWS / 4, 256, 0, stream>>>(x, stem_ln_w + 512, stem_ln_b + 512, hl);
        gemm_r2<EPI_GELU_BF16, 128><<<dim3(128, 8), 256, 0, stream>>>(
            hl, 512, w1T + i * 524288, 512, stem_b1 + i * 1024, nullptr, Hb, 1024, 512);
        gemm_r2<EPI_RES_BF16, 64><<<dim3(128, 8), 256, 0, stream>>>(
            Hb, 1024, w2T + i * 524288, 1024, stem_b2 + i * 512, x, x, 512, 1024);
    }

    ln_kernel<<<NROWS / 4, 256, 0, stream>>>(x, role_ln_w, role_ln_b, hl);

    tanh_class_kernel<<<dim3(128, 3), 256, 0, stream>>>(hl, wabcT, clsb, uu);

    scan_part_kernel<<<dim3(NB, 64), 64, 0, stream>>>(uu, part);
    scan_combine_kernel<<<NB, 64, 0, stream>>>(part, svec);

    float inv_denom = (float)(6.0 / (2047.0 * 2046.0 * 2045.0));
    final_kernel<<<NB, 64, 0, stream>>>(x, svec, query_ln_w, query_ln_b, Wq, bq, out, inv_denom);
}

// Round 7
// 343.436 us; speedup vs baseline: 1.3534x; 1.0221x over previous
//
#include <hip/hip_runtime.h>

#define NROWS 16384   // B*L
#define LSEQ  2048
#define NB    8

typedef short v8s __attribute__((ext_vector_type(8)));
typedef float v4f __attribute__((ext_vector_type(4)));

__device__ __forceinline__ unsigned short f2bf(float f) {
    unsigned int u = __float_as_uint(f);
    return (unsigned short)((u + 0x7fffu + ((u >> 16) & 1u)) >> 16);
}
__device__ __forceinline__ float bf2f(unsigned short u) {
    return __uint_as_float(((unsigned int)u) << 16);
}

// fast exact-GELU: Abramowitz-Stegun 5-term erf, |err|<1.5e-7
__device__ __forceinline__ float fast_gelu(float v) {
    float z = fabsf(v) * 0.70710678118654752f;
    float t = __builtin_amdgcn_rcpf(1.0f + 0.3275911f * z);
    float poly = t * (0.254829592f + t * (-0.284496736f + t * (1.421413741f +
                 t * (-1.453152027f + t * 1.061405429f))));
    float erfz = 1.0f - poly * __expf(-z * z);
    float er = copysignf(erfz, v);
    return 0.5f * v * (1.0f + er);
}
__device__ __forceinline__ float fast_tanh(float y) {
    float e = __expf(2.0f * y);
    return (e - 1.0f) * __builtin_amdgcn_rcpf(e + 1.0f);
}

// ------- merged setup: embed+LN0 (blocks 0..4095) | weight transposes (4096..6239)
//         | class converts (6240..6242) -------
__global__ __launch_bounds__(256) void setup_kernel(
        const int* __restrict__ ids,
        const float* __restrict__ tok, const float* __restrict__ pos,
        const float* __restrict__ g0, const float* __restrict__ b0,
        unsigned short* __restrict__ x, unsigned short* __restrict__ hl,
        const float* __restrict__ w1, const float* __restrict__ w2,
        const float* __restrict__ wa, const float* __restrict__ wb, const float* __restrict__ wc,
        const float* __restrict__ ca, const float* __restrict__ cb, const float* __restrict__ cc,
        unsigned short* __restrict__ w1T, unsigned short* __restrict__ w2T,
        unsigned short* __restrict__ wabcT, unsigned short* __restrict__ clsb) {
    int blk = blockIdx.x;
    int t = threadIdx.x;
    if (blk < 4096) {
        // embed + pos + LN0, one wave per row
        int wave = t >> 6, lane = t & 63;
        long row = (long)blk * 4 + wave;
        int l = (int)(row & (LSEQ - 1));
        int id = ids[row];
        int d = lane * 8;
        float4 t0 = *(const float4*)(tok + (size_t)id * 512 + d);
        float4 t1 = *(const float4*)(tok + (size_t)id * 512 + d + 4);
        float4 p0 = *(const float4*)(pos + (size_t)l * 512 + d);
        float4 p1 = *(const float4*)(pos + (size_t)l * 512 + d + 4);
        float a[8] = {t0.x + p0.x, t0.y + p0.y, t0.z + p0.z, t0.w + p0.w,
                      t1.x + p1.x, t1.y + p1.y, t1.z + p1.z, t1.w + p1.w};
        unsigned int xp[4];
        #pragma unroll
        for (int i = 0; i < 4; ++i)
            xp[i] = (unsigned int)f2bf(a[2 * i]) | ((unsigned int)f2bf(a[2 * i + 1]) << 16);
        *(uint4*)(x + row * 512 + d) = *(uint4*)xp;
        float s = 0.f, s2 = 0.f;
        #pragma unroll
        for (int i = 0; i < 8; ++i) { s += a[i]; s2 += a[i] * a[i]; }
        #pragma unroll
        for (int o = 32; o > 0; o >>= 1) { s += __shfl_down(s, o); s2 += __shfl_down(s2, o); }
        s = __shfl(s, 0); s2 = __shfl(s2, 0);
        float m = s * (1.0f / 512.0f);
        float rinv = 1.0f / sqrtf(s2 * (1.0f / 512.0f) - m * m + 1e-5f);
        float4 ga = *(const float4*)(g0 + d), gb = *(const float4*)(g0 + d + 4);
        float4 ba = *(const float4*)(b0 + d), bb2 = *(const float4*)(b0 + d + 4);
        float gg[8] = {ga.x, ga.y, ga.z, ga.w, gb.x, gb.y, gb.z, gb.w};
        float bb[8] = {ba.x, ba.y, ba.z, ba.w, bb2.x, bb2.y, bb2.z, bb2.w};
        unsigned int hp[4];
        #pragma unroll
        for (int i = 0; i < 4; ++i) {
            unsigned short lo = f2bf((a[2 * i]     - m) * rinv * gg[2 * i]     + bb[2 * i]);
            unsigned short hi = f2bf((a[2 * i + 1] - m) * rinv * gg[2 * i + 1] + bb[2 * i + 1]);
            hp[i] = (unsigned int)lo | ((unsigned int)hi << 16);
        }
        *(uint4*)(hl + row * 512 + d) = *(uint4*)hp;
    } else if (blk < 6240) {
        int id = blk - 4096;
        int tx = t & 31, ty = t >> 5;
        const float* in; unsigned short* out; int R, C, bx, by, ldo;
        if (id < 1024) {
            int l = id >> 9, r = id & 511;
            in = w1 + l * 524288; out = w1T + l * 524288;
            R = 512; C = 1024; bx = r & 31; by = r >> 5; ldo = 512;
        } else if (id < 2048) {
            int l = (id - 1024) >> 9, r = (id - 1024) & 511;
            in = w2 + l * 524288; out = w2T + l * 524288;
            R = 1024; C = 512; bx = r & 15; by = r >> 4; ldo = 1024;
        } else {
            int g = (id - 2048) >> 5, r = (id - 2048) & 31;
            in = (g == 0) ? wa : (g == 1) ? wb : wc;
            out = wabcT + g * 32768;
            R = 512; C = 64; bx = r & 1; by = r >> 1; ldo = 512;
        }
        __shared__ unsigned short tile[32][33];
        int c0 = bx * 32, r0 = by * 32;
        for (int i = ty; i < 32; i += 8) {
            int r = r0 + i, c = c0 + tx;
            tile[i][tx] = (r < R && c < C) ? f2bf(in[(size_t)r * C + c]) : (unsigned short)0;
        }
        __syncthreads();
        for (int i = ty; i < 32; i += 8) {
            int c = c0 + i, r = r0 + tx;
            if (r < R && c < C) out[(size_t)c * ldo + r] = tile[tx][i];
        }
    } else {
        int g = blk - 6240;
        const float* src = (g == 0) ? ca : (g == 1) ? cb : cc;
        unsigned short* dst = clsb + g * 4096;
        for (int i = t; i < 4096; i += 256) dst[i] = f2bf(src[i]);
    }
}

// ------- LayerNorm, one wave per row -------
__global__ __launch_bounds__(256) void ln_kernel(const unsigned short* __restrict__ x,
        const float* __restrict__ g, const float* __restrict__ b,
        unsigned short* __restrict__ out) {
    int wave = threadIdx.x >> 6, lane = threadIdx.x & 63;
    long row = (long)blockIdx.x * 4 + wave;
    int d = lane * 8;
    uint4 xp = *(const uint4*)(x + row * 512 + d);
    const unsigned int* xw = (const unsigned int*)&xp;
    float a[8];
    #pragma unroll
    for (int i = 0; i < 4; ++i) {
        a[2 * i]     = bf2f((unsigned short)(xw[i] & 0xffff));
        a[2 * i + 1] = bf2f((unsigned short)(xw[i] >> 16));
    }
    float s = 0.f, s2 = 0.f;
    #pragma unroll
    for (int i = 0; i < 8; ++i) { s += a[i]; s2 += a[i] * a[i]; }
    #pragma unroll
    for (int o = 32; o > 0; o >>= 1) { s += __shfl_down(s, o); s2 += __shfl_down(s2, o); }
    s = __shfl(s, 0); s2 = __shfl(s2, 0);
    float m = s * (1.0f / 512.0f);
    float rinv = 1.0f / sqrtf(s2 * (1.0f / 512.0f) - m * m + 1e-5f);
    float4 g0 = *(const float4*)(g + d), g1 = *(const float4*)(g + d + 4);
    float4 b0 = *(const float4*)(b + d), b1 = *(const float4*)(b + d + 4);
    float gg[8] = {g0.x, g0.y, g0.z, g0.w, g1.x, g1.y, g1.z, g1.w};
    float bb[8] = {b0.x, b0.y, b0.z, b0.w, b1.x, b1.y, b1.z, b1.w};
    unsigned int hp[4];
    #pragma unroll
    for (int i = 0; i < 4; ++i) {
        unsigned short lo = f2bf((a[2 * i]     - m) * rinv * gg[2 * i]     + bb[2 * i]);
        unsigned short hi = f2bf((a[2 * i + 1] - m) * rinv * gg[2 * i + 1] + bb[2 * i + 1]);
        hp[i] = (unsigned int)lo | ((unsigned int)hi << 16);
    }
    *(uint4*)(out + row * 512 + d) = *(uint4*)hp;
}

// ------- MFMA GEMM: R2 2-barrier structure + swapped-operand packed epilogue -------
#define EPI_GELU_BF16  0
#define EPI_RES_BF16   1

template <int EPI, int TN>
__global__ __launch_bounds__(256) void gemm_r2(
        const unsigned short* __restrict__ A, int lda,
        const unsigned short* __restrict__ BT, int ldb,
        const float* __restrict__ bias,
        const unsigned short* __restrict__ xres,
        unsigned short* __restrict__ Cout, int ldc, int K) {
    constexpr int NJ = TN / 32;
    __shared__ unsigned short As[128][40] __attribute__((aligned(16)));
    __shared__ unsigned short Bs[TN][40] __attribute__((aligned(16)));
    const int t = threadIdx.x;
    const int lane = t & 63, wave = t >> 6;
    const int quad = lane >> 4, l16 = lane & 15;
    const int wm = (wave >> 1) * 64, wn = (wave & 1) * (TN / 2);
    const long tileM = (long)blockIdx.x * 128, tileN = (long)blockIdx.y * TN;
    const int arow = t >> 2, acol = (t & 3) * 8;

    const unsigned short* gA0 = A + (tileM + arow) * lda + acol;
    const unsigned short* gA1 = gA0 + 64 * (long)lda;
    const unsigned short* gB0 = BT + (tileN + arow) * ldb + acol;
    const unsigned short* gB1 = gB0 + 64 * (long)ldb;

    v4f acc[4][NJ] = {};
    uint4 a0, a1, b0, b1;

    a0 = *(const uint4*)gA0; a1 = *(const uint4*)gA1; gA0 += 32; gA1 += 32;
    b0 = *(const uint4*)gB0; gB0 += 32;
    if (TN == 128) { b1 = *(const uint4*)gB1; gB1 += 32; }
    *(uint4*)&As[arow][acol] = a0;
    *(uint4*)&As[arow + 64][acol] = a1;
    *(uint4*)&Bs[arow][acol] = b0;
    if (TN == 128) *(uint4*)&Bs[arow + 64][acol] = b1;

    const int nk = K >> 5;
    for (int kk = 0; kk < nk; ++kk) {
        __syncthreads();
        const bool more = kk + 1 < nk;
        if (more) {
            a0 = *(const uint4*)gA0; a1 = *(const uint4*)gA1; gA0 += 32; gA1 += 32;
            b0 = *(const uint4*)gB0; gB0 += 32;
            if (TN == 128) { b1 = *(const uint4*)gB1; gB1 += 32; }
        }
        v8s af[4], bfr[NJ];
        #pragma unroll
        for (int i = 0; i < 4; ++i) af[i] = *(const v8s*)&As[wm + i * 16 + l16][quad * 8];
        #pragma unroll
        for (int j = 0; j < NJ; ++j) bfr[j] = *(const v8s*)&Bs[wn + j * 16 + l16][quad * 8];
        #pragma unroll
        for (int i = 0; i < 4; ++i)
            #pragma unroll
            for (int j = 0; j < NJ; ++j)
                acc[i][j] = __builtin_amdgcn_mfma_f32_16x16x32_bf16(bfr[j], af[i], acc[i][j], 0, 0, 0);
        __syncthreads();
        if (more) {
            *(uint4*)&As[arow][acol] = a0;
            *(uint4*)&As[arow + 64][acol] = a1;
            *(uint4*)&Bs[arow][acol] = b0;
            if (TN == 128) *(uint4*)&Bs[arow + 64][acol] = b1;
        }
    }

    // packed epilogue: fixed m per lane, 4 consecutive n per acc
    #pragma unroll
    for (int i = 0; i < 4; ++i) {
        long m = tileM + wm + i * 16 + l16;
        #pragma unroll
        for (int j = 0; j < NJ; ++j) {
            long n0 = tileN + wn + j * 16 + quad * 4;
            float4 bi = *(const float4*)&bias[n0];
            const float* bip = (const float*)&bi;
            unsigned short pk[4];
            if (EPI == EPI_GELU_BF16) {
                #pragma unroll
                for (int r = 0; r < 4; ++r)
                    pk[r] = f2bf(fast_gelu(acc[i][j][r] + bip[r]));
            } else {
                ushort4 xr4 = *(const ushort4*)&xres[m * ldc + n0];
                const unsigned short* xp = (const unsigned short*)&xr4;
                #pragma unroll
                for (int r = 0; r < 4; ++r)
                    pk[r] = f2bf(acc[i][j][r] + bip[r] + bf2f(xp[r]));
            }
            *(ushort4*)&Cout[m * ldc + n0] = *(ushort4*)pk;
        }
    }
}

// ------- fused tanh-GEMM + class-GEMM, R2-structure K-loop -------
__global__ __launch_bounds__(256) void tanh_class_kernel(
        const unsigned short* __restrict__ A,
        const unsigned short* __restrict__ WT,
        const unsigned short* __restrict__ cls,
        unsigned short* __restrict__ uu) {
    __shared__ unsigned short As[128][40] __attribute__((aligned(16)));
    __shared__ unsigned short Bs[64][40] __attribute__((aligned(16)));
    __shared__ unsigned short P[128 * 72] __attribute__((aligned(16)));
    const int t = threadIdx.x;
    const int lane = t & 63, wave = t >> 6;
    const int quad = lane >> 4, l16 = lane & 15;
    const int wm = (wave >> 1) * 64, wn = (wave & 1) * 32;
    const long tileM = (long)blockIdx.x * 128;
    const int g = blockIdx.y;
    const int arow = t >> 2, acol = (t & 3) * 8;

    const unsigned short* BT = WT + g * 32768;
    v8s cf[2][2];
    #pragma unroll
    for (int ks = 0; ks < 2; ++ks)
        #pragma unroll
        for (int j = 0; j < 2; ++j)
            cf[ks][j] = *(const v8s*)&cls[g * 4096 + (wn + j * 16 + l16) * 64 + ks * 32 + quad * 8];

    const unsigned short* gA0 = A + (tileM + arow) * 512 + acol;
    const unsigned short* gA1 = gA0 + 64 * 512;
    const unsigned short* gB0 = BT + arow * 512 + acol;

    v4f acc[4][2] = {};
    uint4 a0, a1, b0;
    a0 = *(const uint4*)gA0; a1 = *(const uint4*)gA1; gA0 += 32; gA1 += 32;
    b0 = *(const uint4*)gB0; gB0 += 32;
    *(uint4*)&As[arow][acol] = a0;
    *(uint4*)&As[arow + 64][acol] = a1;
    *(uint4*)&Bs[arow][acol] = b0;

    for (int kk = 0; kk < 16; ++kk) {
        __syncthreads();
        const bool more = kk < 15;
        if (more) {
            a0 = *(const uint4*)gA0; a1 = *(const uint4*)gA1; gA0 += 32; gA1 += 32;
            b0 = *(const uint4*)gB0; gB0 += 32;
        }
        v8s af[4], bfr[2];
        #pragma unroll
        for (int i = 0; i < 4; ++i) af[i] = *(const v8s*)&As[wm + i * 16 + l16][quad * 8];
        #pragma unroll
        for (int j = 0; j < 2; ++j) bfr[j] = *(const v8s*)&Bs[wn + j * 16 + l16][quad * 8];
        #pragma unroll
        for (int i = 0; i < 4; ++i)
            #pragma unroll
            for (int j = 0; j < 2; ++j)
                acc[i][j] = __builtin_amdgcn_mfma_f32_16x16x32_bf16(bfr[j], af[i], acc[i][j], 0, 0, 0);
        __syncthreads();
        if (more) {
            *(uint4*)&As[arow][acol] = a0;
            *(uint4*)&As[arow + 64][acol] = a1;
            *(uint4*)&Bs[arow][acol] = b0;
        }
    }

    // P[m][n] packed: per lane m = wm+i*16+l16, n0 = wn+j*16+quad*4
    #pragma unroll
    for (int i = 0; i < 4; ++i) {
        int m = wm + i * 16 + l16;
        #pragma unroll
        for (int j = 0; j < 2; ++j) {
            int n0 = wn + j * 16 + quad * 4;
            unsigned short pk[4];
            #pragma unroll
            for (int r = 0; r < 4; ++r) pk[r] = f2bf(fast_tanh(acc[i][j][r]));
            *(ushort4*)&P[m * 72 + n0] = *(ushort4*)pk;
        }
    }
    __syncthreads();

    v4f acc2[4][2] = {};
    #pragma unroll
    for (int ks = 0; ks < 2; ++ks) {
        v8s paf[4];
        #pragma unroll
        for (int i = 0; i < 4; ++i)
            paf[i] = *(const v8s*)&P[(wm + i * 16 + l16) * 72 + ks * 32 + quad * 8];
        #pragma unroll
        for (int i = 0; i < 4; ++i)
            #pragma unroll
            for (int j = 0; j < 2; ++j)
                acc2[i][j] = __builtin_amdgcn_mfma_f32_16x16x32_bf16(cf[ks][j], paf[i], acc2[i][j], 0, 0, 0);
    }

    #pragma unroll
    for (int i = 0; i < 4; ++i) {
        long m = tileM + wm + i * 16 + l16;
        #pragma unroll
        for (int j = 0; j < 2; ++j) {
            int c0 = wn + j * 16 + quad * 4;
            unsigned short pk[4];
            #pragma unroll
            for (int r = 0; r < 4; ++r) pk[r] = f2bf(acc2[i][j][r]);
            *(ushort4*)&uu[m * 192 + g * 64 + c0] = *(ushort4*)pk;
        }
    }
}

// ------- exact ordered-triplet scan pass 1 -------
__global__ __launch_bounds__(64) void scan_part_kernel(const unsigned short* __restrict__ u,
                                                       float* __restrict__ part) {
    int b = blockIdx.x, seg = blockIdx.y;
    int c = threadIdx.x;
    int l0 = seg * 32;
    int l1 = l0 + 32; if (l1 > 2047) l1 = 2047;
    float sA = 0.f, sB = 0.f, sC = 0.f, T = 0.f, M = 0.f, U = 0.f;
    const unsigned short* base = u + ((size_t)b * LSEQ + l0) * 192 + c;
    for (int l = l0; l < l1; ++l) {
        float ua = bf2f(base[0]), ub = bf2f(base[64]), uc = bf2f(base[128]);
        base += 192;
        U += uc * T;
        M += uc * sB;
        T += ub * sA;
        sA += ua; sB += ub; sC += uc;
    }
    float* p = part + ((size_t)(b * 64 + seg)) * 384 + c;
    p[0] = sA; p[64] = sB; p[128] = sC; p[192] = T; p[256] = M; p[320] = U;
}

// ------- merged: segment combine + final LN + Wq GEMV -------
__global__ __launch_bounds__(64) void combine_final_kernel(const float* __restrict__ part,
        const unsigned short* __restrict__ x,
        const float* __restrict__ qw, const float* __restrict__ qb,
        const float* __restrict__ Wq, const float* __restrict__ bq,
        float* __restrict__ out, float inv_denom) {
    int b = blockIdx.x;
    int c = threadIdx.x;
    // combine 64 segment-partials (ordered)
    const float* p = part + (size_t)b * 64 * 384 + c;
    float A = p[0], B = p[64], Tt = p[192], Mt = p[256], Ut = p[320];
    for (int seg = 1; seg < 64; ++seg) {
        const float* q2 = p + seg * 384;
        float a2 = q2[0], b2 = q2[64], c2 = q2[128], t2 = q2[192], m2 = q2[256], u2 = q2[320];
        float Un = Ut + u2 + c2 * Tt + A * m2;
        float Tn = Tt + t2 + A * b2;
        float Mn = Mt + m2 + B * c2;
        A += a2; B += b2;
        Ut = Un; Tt = Tn; Mt = Mn;
    }
    // final LN + GEMV
    __shared__ float q[512];
    __shared__ float mv[2];
    const unsigned short* xr = x + ((size_t)b * LSEQ + (LSEQ - 1)) * 512;
    float s1 = 0.f, s2 = 0.f;
    for (int i = c; i < 512; i += 64) { float v = bf2f(xr[i]); q[i] = v; s1 += v; s2 += v * v; }
    #pragma unroll
    for (int o = 32; o > 0; o >>= 1) { s1 += __shfl_down(s1, o); s2 += __shfl_down(s2, o); }
    if (c == 0) {
        float m = s1 * (1.0f / 512.0f);
        float var = s2 * (1.0f / 512.0f) - m * m;
        mv[0] = m; mv[1] = 1.0f / sqrtf(var + 1e-5f);
    }
    __syncthreads();
    float m = mv[0], r = mv[1];
    for (int i = c; i < 512; i += 64) q[i] = (q[i] - m) * r * qw[i] + qb[i];
    __syncthreads();
    float acc = 0.f;
    for (int d = 0; d < 512; ++d) acc += q[d] * Wq[d * 64 + c];
    out[b * 64 + c] = Ut * inv_denom + acc + bq[c];
}

extern "C" void kernel_launch(void* const* d_in, const int* in_sizes, int n_in,
                              void* d_out, int out_size, void* d_ws, size_t ws_size,
                              hipStream_t stream) {
    const int*   token_ids   = (const int*)d_in[0];
    const float* tok_emb     = (const float*)d_in[1];
    const float* pos_emb     = (const float*)d_in[2];
    const float* stem_ln_w   = (const float*)d_in[3];
    const float* stem_ln_b   = (const float*)d_in[4];
    const float* stem_w1     = (const float*)d_in[5];
    const float* stem_b1     = (const float*)d_in[6];
    const float* stem_w2     = (const float*)d_in[7];
    const float* stem_b2     = (const float*)d_in[8];
    const float* role_ln_w   = (const float*)d_in[9];
    const float* role_ln_b   = (const float*)d_in[10];
    const float* Wa          = (const float*)d_in[11];
    const float* Wb          = (const float*)d_in[12];
    const float* Wc          = (const float*)d_in[13];
    const float* class_a     = (const float*)d_in[14];
    const float* class_b     = (const float*)d_in[15];
    const float* class_c     = (const float*)d_in[16];
    const float* query_ln_w  = (const float*)d_in[17];
    const float* query_ln_b  = (const float*)d_in[18];
    const float* Wq          = (const float*)d_in[19];
    const float* bq          = (const float*)d_in[20];
    float* out = (float*)d_out;

    char* wsb = (char*)d_ws;
    unsigned short* x    = (unsigned short*)(wsb);              // 16,777,216
    unsigned short* hl   = (unsigned short*)(wsb + 16777216);   // 16,777,216
    unsigned short* Hb   = (unsigned short*)(wsb + 33554432);   // 33,554,432
    unsigned short* uu   = (unsigned short*)(wsb + 67108864);   // 6,291,456
    float* part          = (float*)(wsb + 73400320);            // 786,432
    unsigned short* w1T  = (unsigned short*)(wsb + 74188800);   // 2,097,152
    unsigned short* w2T  = (unsigned short*)(wsb + 76285952);   // 2,097,152
    unsigned short* wabcT= (unsigned short*)(wsb + 78383104);   // 196,608
    unsigned short* clsb = (unsigned short*)(wsb + 78579712);   // 24,576

    setup_kernel<<<6243, 256, 0, stream>>>(token_ids, tok_emb, pos_emb,
        stem_ln_w, stem_ln_b, x, hl,
        stem_w1, stem_w2, Wa, Wb, Wc, class_a, class_b, class_c,
        w1T, w2T, wabcT, clsb);

    for (int i = 0; i < 2; ++i) {
        if (i > 0)
            ln_kernel<<<NROWS / 4, 256, 0, stream>>>(x, stem_ln_w + 512, stem_ln_b + 512, hl);
        gemm_r2<EPI_GELU_BF16, 128><<<dim3(128, 8), 256, 0, stream>>>(
            hl, 512, w1T + i * 524288, 512, stem_b1 + i * 1024, nullptr, Hb, 1024, 512);
        gemm_r2<EPI_RES_BF16, 64><<<dim3(128, 8), 256, 0, stream>>>(
            Hb, 1024, w2T + i * 524288, 1024, stem_b2 + i * 512, x, x, 512, 1024);
    }

    ln_kernel<<<NROWS / 4, 256, 0, stream>>>(x, role_ln_w, role_ln_b, hl);

    tanh_class_kernel<<<dim3(128, 3), 256, 0, stream>>>(hl, wabcT, clsb, uu);

    scan_part_kernel<<<dim3(NB, 64), 64, 0, stream>>>(uu, part);

    float inv_denom = (float)(6.0 / (2047.0 * 2046.0 * 2045.0));
    combine_final_kernel<<<NB, 64, 0, stream>>>(part, x, query_ln_w, query_ln_b,
                                                Wq, bq, out, inv_denom);
}